// Round 1
// 171.581 us; speedup vs baseline: 1.0247x; 1.0247x over previous
//
#include <hip/hip_runtime.h>
#include <math.h>

#define B_ 4
#define L_ 2048
#define S_ 2048
#define H_ 8
#define E_ 64
#define BH_ (B_*H_)
#define EPS 1e-6f

typedef __attribute__((ext_vector_type(8))) short short8;
typedef __attribute__((ext_vector_type(4))) float f32x4;

__device__ __forceinline__ unsigned short f2bf(float f) {
    unsigned int u = __float_as_uint(f);
    u = (u + 0x7fffu + ((u >> 16) & 1u)) >> 16;   // RNE
    return (unsigned short)u;
}

__device__ __forceinline__ float bf2f(unsigned short u) {
    return __uint_as_float(((unsigned int)u) << 16);
}

__device__ __forceinline__ float fast_tanh(float x) {
    float e = __expf(2.0f * x);
    return 1.0f - 2.0f / (e + 1.0f);
}

// XOR-swizzled LDS byte offset: rows of 128B, 16B chunks swizzled by row&7.
// Measured 0 bank conflicts for the K staging + frag-read pattern (round 2).
__device__ __forceinline__ int swb(int row, int byteoff) {
    return row * 128 + ((((byteoff >> 4) ^ (row & 7)) << 4) | (byteoff & 15));
}

// ---------------------------------------------------------------------------
// K0 (fused preprocessing, partitioned grid):
//  blocks [0,2048):    q transform  -> qt  [B,H,L,E] bf16
//  blocks [2048,4096): k transform  -> kt  [B,H,S,E] bf16
//  blocks [4096,5120): v transform  -> vt  MFMA-frag-tiled bf16:
//        vt[bh][st][ri*8+j], ri = et*128+c*64+quad*16+m,
//        value = V[b][st*64 + c*32+quad*8+j][h][et*16+m]
//        -> attn's vf[c][et] load is contiguous: lane reads ri=own, 16B.
// transform: std over H axis (8 vals, ddof=1); tanh(x*dw/(std+eps))*dp
// ---------------------------------------------------------------------------
__global__ __launch_bounds__(256) void pre_kernel(
    const float* __restrict__ xq, const float* __restrict__ xk,
    const float* __restrict__ xv,
    unsigned short* __restrict__ qt, unsigned short* __restrict__ kt,
    unsigned short* __restrict__ vt,
    const float* __restrict__ dwp, const float* __restrict__ dpp)
{
    __shared__ float ls[64][65];
    int bx = blockIdx.x;
    if (bx < 4096) {
        const float* x = (bx < 2048) ? xq : xk;
        unsigned short* xt = (bx < 2048) ? qt : kt;
        int g = (bx & 2047) * 256 + threadIdx.x;   // over B*L*E = 524288
        int e = g & 63;
        int bl = g >> 6;
        int b = bl >> 11;
        int l = bl & 2047;
        size_t base = (size_t)bl * (H_ * E_) + e;
        float v[8], s = 0.f, q = 0.f;
#pragma unroll
        for (int h = 0; h < 8; ++h) {
            float t = x[base + h * E_];
            v[h] = t; s += t; q += t * t;
        }
        float mean = s * 0.125f;
        float var = (q - s * mean) * (1.f / 7.f);   // ddof=1, N=8
        var = fmaxf(var, 0.f);
        float inv = 1.f / (sqrtf(var) + EPS);
        float wsc = dwp[0] * inv;
        float d = dpp[0];
#pragma unroll
        for (int h = 0; h < 8; ++h) {
            float t = fast_tanh(v[h] * wsc) * d;
            xt[((size_t)(b * H_ + h) * L_ + l) * E_ + e] = f2bf(t);
        }
    } else {
        int t2 = bx - 4096;
        int s0 = (t2 & 31) * 64;
        int h = (t2 >> 5) & 7, b = t2 >> 8;
        int t = threadIdx.x;
#pragma unroll
        for (int i = 0; i < 4; ++i) {
            int idx = t + i * 256;
            int r = idx >> 4, c4 = (idx & 15) * 4;
            const float4 f = *(const float4*)&xv[((size_t)(b * S_ + s0 + r) * H_ + h) * E_ + c4];
            ls[r][c4] = f.x; ls[r][c4 + 1] = f.y; ls[r][c4 + 2] = f.z; ls[r][c4 + 3] = f.w;
        }
        __syncthreads();
        size_t ob = ((size_t)(b * H_ + h) * (S_ / 64) + (s0 >> 6)) * 4096;
#pragma unroll
        for (int i = 0; i < 2; ++i) {
            int ri = t + i * 256;                  // 512 runs of 8 halfwords
            int et = ri >> 7, c = (ri >> 6) & 1, quad = (ri >> 4) & 3, m = ri & 15;
            int e = et * 16 + m, sb = c * 32 + quad * 8;
            unsigned short tmp[8];
#pragma unroll
            for (int j = 0; j < 8; ++j) tmp[j] = f2bf(ls[sb + j][e]);
            *(uint4*)&vt[ob + (size_t)ri * 8] = *(uint4*)tmp;
        }
    }
}

// ---------------------------------------------------------------------------
// K1: per (b,h): G = Kt^T Kt (64x64 f32 acc -> bf16) + ksum[e] = sum_s kt.
// 32 blocks, 256 thr. Reads kt in 16 chunks of 128 s (reg-prefetched),
// in-LDS transpose for the A==B fragments, 256 MFMA/wave, 4-wave reduce.
// ---------------------------------------------------------------------------
__global__ __launch_bounds__(256) void gram_kernel(
    const unsigned short* __restrict__ kt, unsigned short* __restrict__ Gb,
    float* __restrict__ ksum)
{
    __shared__ unsigned short ks[128 * 72];   // pad 72: transpose-friendly
    __shared__ float gs[4096];
    __shared__ float kss[64];
    int bh = blockIdx.x;
    const unsigned short* base = kt + (size_t)bh * S_ * E_;
    int tid = threadIdx.x, lane = tid & 63, w = tid >> 6;
    int m = lane & 15, quad = lane >> 4;

    f32x4 acc[4][4];
#pragma unroll
    for (int i = 0; i < 4; ++i)
#pragma unroll
        for (int j = 0; j < 4; ++j) acc[i][j] = (f32x4){0.f, 0.f, 0.f, 0.f};
    float ksp[4] = {0.f, 0.f, 0.f, 0.f};

    short8 stg[4];
#pragma unroll
    for (int i = 0; i < 4; ++i)
        stg[i] = *(const short8*)(base + (size_t)(tid + i * 256) * 8);

    for (int ch = 0; ch < 16; ++ch) {
        __syncthreads();                       // prior readers of ks done
#pragma unroll
        for (int i = 0; i < 4; ++i) {
            int u = tid + i * 256;
            *(short8*)&ks[(u >> 3) * 72 + (u & 7) * 8] = stg[i];
        }
        __syncthreads();
        if (ch < 15) {
#pragma unroll
            for (int i = 0; i < 4; ++i)
                stg[i] = *(const short8*)(base + (size_t)(ch + 1) * 8192 + (tid + i * 256) * 8);
        }
        int s0 = w * 32;
        short8 af[4];
#pragma unroll
        for (int i = 0; i < 4; ++i) {
            short8 a;
#pragma unroll
            for (int kk = 0; kk < 8; ++kk) {
                unsigned short uv = ks[(s0 + quad * 8 + kk) * 72 + i * 16 + m];
                a[kk] = (short)uv;
                ksp[i] += bf2f(uv);
            }
            af[i] = a;
        }
#pragma unroll
        for (int i = 0; i < 4; ++i)
#pragma unroll
            for (int j = 0; j < 4; ++j)
                acc[i][j] = __builtin_amdgcn_mfma_f32_16x16x32_bf16(af[i], af[j], acc[i][j], 0, 0, 0);
    }
#pragma unroll
    for (int i = 0; i < 4; ++i) {
        ksp[i] += __shfl_xor(ksp[i], 16);
        ksp[i] += __shfl_xor(ksp[i], 32);
    }
    for (int w2 = 0; w2 < 4; ++w2) {
        if (w == w2) {
#pragma unroll
            for (int i = 0; i < 4; ++i)
#pragma unroll
                for (int j = 0; j < 4; ++j)
#pragma unroll
                    for (int r = 0; r < 4; ++r) {
                        int idx = (i * 16 + quad * 4 + r) * 64 + j * 16 + m;
                        if (w2 == 0) gs[idx] = acc[i][j][r]; else gs[idx] += acc[i][j][r];
                    }
            if (lane < 16) {
#pragma unroll
                for (int i = 0; i < 4; ++i) {
                    int e = i * 16 + lane;
                    if (w2 == 0) kss[e] = ksp[i]; else kss[e] += ksp[i];
                }
            }
        }
        __syncthreads();
    }
#pragma unroll
    for (int ii = 0; ii < 16; ++ii) {
        int idx = tid + ii * 256;
        Gb[(size_t)bh * 4096 + idx] = f2bf(gs[idx]);
    }
    if (tid < 64) ksum[bh * 64 + tid] = kss[tid];
}

// ---------------------------------------------------------------------------
// K2: single-pass attention. ROUND-5 RESTRUCTURE: 512 threads = 8 waves x
// 16 q-rows (was 4 waves x 32). Grid stays 512 -> 2 blocks/CU = 16 waves/CU
// (4 waves/SIMD, was 2): doubles the latency-hiding pool at ZERO extra
// global traffic (K stage per block unchanged: exactly 1 uint4/thread).
// All swizzled LDS offsets hoisted to registers before the loop; kf1/pf1
// addresses derived via ^64 (chunk bit2 -> byte bit6 is XOR-linear through
// the swizzle). K staged in LDS (reg-prefetch dbuf, one barrier/iter);
// V frags DIRECT from frag-tiled global; P round-trips wave-private LDS
// (2KB/wave now). Alpha from Gram quadratic-form trick (in-block).
// ---------------------------------------------------------------------------
__global__ __launch_bounds__(512, 4) void attn_kernel(
    const unsigned short* __restrict__ qt,
    const unsigned short* __restrict__ kt,
    const unsigned short* __restrict__ vt,
    const unsigned short* __restrict__ Gb,
    const float* __restrict__ ksum,
    float* __restrict__ out)
{
    __shared__ __align__(16) char lds[33792];
    // [0,16384): K double buffer (2 x 8KB, swizzled 128B rows)
    // [16384,32768): wave-private P (8 x 2KB)
    // [32768,33792): alpha scratch (8 x 16 float2)
    const int tid = threadIdx.x;
    const int lane = tid & 63;
    const int w = tid >> 6;
    const int m = lane & 15;
    const int quad = lane >> 4;
    char* ptb = lds + 16384 + w * 2048;
    float2* ascr = (float2*)(lds + 32768) + w * 16;

    int blk = blockIdx.x;
    int bh = (blk & 7) * 4 + ((blk >> 3) & 3);   // XCD swizzle: 4 bh per XCD
    int l0 = (blk >> 5) * 128;
    int b = bh >> 3, h = bh & 7;

    const unsigned short* qtb = qt + (size_t)bh * L_ * E_;
    const unsigned short* ktb = kt + (size_t)bh * S_ * E_;
    const unsigned short* vtb = vt + (size_t)bh * (S_ / 64) * 4096;

    // Q B-fragments (register-resident): lane m <-> q-row l0 + w*16 + m
    short8 qf[2];
#pragma unroll
    for (int c = 0; c < 2; ++c)
        qf[c] = *(const short8*)(qtb + (size_t)(l0 + w * 16 + m) * E_ + c * 32 + quad * 8);

    // ---- in-block alpha: T = Q*G, sumsq = sum T.Q, rowsum = Q.ksum ----
    float al, alm;
    {
        const unsigned short* gb = Gb + (size_t)bh * 4096;
        short8 gfr[4][2];
#pragma unroll
        for (int j = 0; j < 4; ++j)
#pragma unroll
            for (int c = 0; c < 2; ++c)
                gfr[j][c] = *(const short8*)(gb + (size_t)(j * 16 + m) * 64 + c * 32 + quad * 8);
        float ksl[4];
#pragma unroll
        for (int j = 0; j < 4; ++j) ksl[j] = ksum[bh * 64 + j * 16 + m];
        f32x4 accj[4];
#pragma unroll
        for (int j = 0; j < 4; ++j) {
            accj[j] = (f32x4){0.f, 0.f, 0.f, 0.f};
            accj[j] = __builtin_amdgcn_mfma_f32_16x16x32_bf16(qf[0], gfr[j][0], accj[j], 0, 0, 0);
            accj[j] = __builtin_amdgcn_mfma_f32_16x16x32_bf16(qf[1], gfr[j][1], accj[j], 0, 0, 0);
        }
        float ps[4] = {0, 0, 0, 0}, pr[4] = {0, 0, 0, 0};
#pragma unroll
        for (int r = 0; r < 4; ++r)
#pragma unroll
            for (int j = 0; j < 4; ++j) {
                float qv = bf2f(qtb[(size_t)(l0 + w * 16 + quad * 4 + r) * E_ + j * 16 + m]);
                ps[r] = fmaf(accj[j][r], qv, ps[r]);
                pr[r] = fmaf(qv, ksl[j], pr[r]);
            }
#pragma unroll
        for (int mask = 1; mask < 16; mask <<= 1)
#pragma unroll
            for (int r = 0; r < 4; ++r) {
                ps[r] += __shfl_xor(ps[r], mask);
                pr[r] += __shfl_xor(pr[r], mask);
            }
        if (m == 0) {
#pragma unroll
            for (int r = 0; r < 4; ++r) {
                float sum = pr[r];
                float mu = sum * (1.f / S_);
                float var = (ps[r] - sum * mu) * (1.f / (S_ - 1));   // ddof=1
                var = fmaxf(var, 0.f);
                float tau = sqrtf(var + EPS);
                float a = 0.125f / tau;                               // scale=1/8
                ascr[quad * 4 + r] = make_float2(a, a * mu);
            }
        }
        float2 a2 = ascr[m];   // wave-private LDS: lgkmcnt ordering suffices
        al = a2.x; alm = a2.y;
    }

    float dsum = 0.f;
    f32x4 oacc[4];
#pragma unroll
    for (int et = 0; et < 4; ++et) oacc[et] = (f32x4){0.f, 0.f, 0.f, 0.f};

    // ---- hoisted swizzled LDS offsets (loop-invariant, stay in VGPRs) ----
    int ko[4], pw[4];
#pragma unroll
    for (int nt = 0; nt < 4; ++nt) {
        ko[nt] = swb(nt * 16 + m, quad * 16);        // K frag read (c=0); c=1 is ^64
        pw[nt] = swb(m, nt * 32 + quad * 8);         // P uint2 write
    }
    const int pr0 = swb(m, quad * 16);               // P frag read (c=0); c=1 is ^64
    const int stg = swb(tid >> 3, (tid & 7) * 16);   // K stage write (1 uint4/thread)

    // preload K tile 0 (8KB = 512 uint4, 1 per thread)
    uint4 kr = *(const uint4*)(ktb + (size_t)tid * 8);
    *(uint4*)(lds + stg) = kr;
    __syncthreads();

    auto step = [&](int st, char* kcur, char* knxt) {
        // prefetch next K tile into registers (covered by loop-end barrier)
        if (st < S_ / 64 - 1)
            kr = *(const uint4*)(ktb + (size_t)(st + 1) * 4096 + (size_t)tid * 8);
        // V B-frags: contiguous 1KB wave-loads from frag-tiled vt
        const unsigned short* vstb = vtb + (size_t)st * 4096;
        short8 vf[2][4];
#pragma unroll
        for (int c = 0; c < 2; ++c)
#pragma unroll
            for (int et = 0; et < 4; ++et)
                vf[c][et] = *(const short8*)(vstb + et * 1024 + c * 512 + lane * 8);

        // QK: scores transposed (lane m = q-row, s in (nt,quad,r))
#pragma unroll
        for (int nt = 0; nt < 4; ++nt) {
            short8 kf0 = *(const short8*)(kcur + ko[nt]);
            short8 kf1 = *(const short8*)(kcur + (ko[nt] ^ 64));
            f32x4 acc = (f32x4){0.f, 0.f, 0.f, 0.f};
            acc = __builtin_amdgcn_mfma_f32_16x16x32_bf16(kf0, qf[0], acc, 0, 0, 0);
            acc = __builtin_amdgcn_mfma_f32_16x16x32_bf16(kf1, qf[1], acc, 0, 0, 0);
            unsigned int u0, u1, u2, u3;
            {
                float p0 = __expf(fmaf(al, acc[0], -alm));
                float p1 = __expf(fmaf(al, acc[1], -alm));
                float p2 = __expf(fmaf(al, acc[2], -alm));
                float p3 = __expf(fmaf(al, acc[3], -alm));
                u0 = __float_as_uint(p0) & 0xffff0000u;
                u1 = __float_as_uint(p1) & 0xffff0000u;
                u2 = __float_as_uint(p2) & 0xffff0000u;
                u3 = __float_as_uint(p3) & 0xffff0000u;
                dsum += __uint_as_float(u0) + __uint_as_float(u1)
                      + __uint_as_float(u2) + __uint_as_float(u3);
            }
            uint2 pk;
            pk.x = (u0 >> 16) | u1;
            pk.y = (u2 >> 16) | u3;
            *(uint2*)(ptb + pw[nt]) = pk;
        }
        // PV (pt wave-private: lgkmcnt ordering suffices, no barrier)
        short8 pf0 = *(const short8*)(ptb + pr0);
        short8 pf1 = *(const short8*)(ptb + (pr0 ^ 64));
#pragma unroll
        for (int et = 0; et < 4; ++et) {
            oacc[et] = __builtin_amdgcn_mfma_f32_16x16x32_bf16(pf0, vf[0][et], oacc[et], 0, 0, 0);
            oacc[et] = __builtin_amdgcn_mfma_f32_16x16x32_bf16(pf1, vf[1][et], oacc[et], 0, 0, 0);
        }
        // write prefetched K to the other buffer; single barrier per iter.
        // (all waves are in the same st between barriers -> read buf != write buf)
        if (st < S_ / 64 - 1)
            *(uint4*)(knxt + stg) = kr;
        __syncthreads();
    };
#pragma unroll 1
    for (int st2 = 0; st2 < S_ / 128; ++st2) {
        step(2 * st2,     lds,        lds + 8192);   // compile-time buffer select
        step(2 * st2 + 1, lds + 8192, lds);
    }

    // denominator reduce over quads, redistribute, store
    dsum += __shfl_xor(dsum, 16);
    dsum += __shfl_xor(dsum, 32);
#pragma unroll
    for (int r = 0; r < 4; ++r) {
        float dn = __shfl(dsum, quad * 4 + r);
        float rd = 1.0f / dn;
        size_t row = (size_t)(b * L_ + l0 + w * 16 + quad * 4 + r);
#pragma unroll
        for (int et = 0; et < 4; ++et)
            out[(row * H_ + h) * E_ + et * 16 + m] = oacc[et][r] * rd;
    }
}

extern "C" void kernel_launch(void* const* d_in, const int* in_sizes, int n_in,
                              void* d_out, int out_size, void* d_ws, size_t ws_size,
                              hipStream_t stream)
{
    const float* q = (const float*)d_in[0];
    const float* k = (const float*)d_in[1];
    const float* v = (const float*)d_in[2];
    // d_in[3] = attn_mask (unused)
    const float* dw = (const float*)d_in[4];
    const float* dp = (const float*)d_in[5];
    float* out = (float*)d_out;

    unsigned short* qt = (unsigned short*)d_ws;              // [B,H,L,E] bf16, 8MB
    unsigned short* kt = qt + (size_t)BH_ * L_ * E_;         // [B,H,S,E] bf16, 8MB
    unsigned short* vt = kt + (size_t)BH_ * S_ * E_;         // frag-tiled, 8MB
    unsigned short* Gb = vt + (size_t)BH_ * E_ * S_;         // [B,H,64,64] bf16
    float* ksum = (float*)(Gb + (size_t)BH_ * 4096);         // [B,H,64]

    pre_kernel<<<5120, 256, 0, stream>>>(q, k, v, qt, kt, vt, dw, dp);
    gram_kernel<<<BH_, 256, 0, stream>>>(kt, Gb, ksum);
    attn_kernel<<<512, 512, 0, stream>>>(qt, kt, vt, Gb, ksum, out);
}

// Round 2
// 168.810 us; speedup vs baseline: 1.0415x; 1.0164x over previous
//
#include <hip/hip_runtime.h>
#include <math.h>

#define B_ 4
#define L_ 2048
#define S_ 2048
#define H_ 8
#define E_ 64
#define BH_ (B_*H_)
#define EPS 1e-6f
#define LOG2E 1.44269504088896340736f

typedef __attribute__((ext_vector_type(8))) short short8;
typedef __attribute__((ext_vector_type(4))) float f32x4;

__device__ __forceinline__ unsigned short f2bf(float f) {
    unsigned int u = __float_as_uint(f);
    u = (u + 0x7fffu + ((u >> 16) & 1u)) >> 16;   // RNE
    return (unsigned short)u;
}

__device__ __forceinline__ float bf2f(unsigned short u) {
    return __uint_as_float(((unsigned int)u) << 16);
}

__device__ __forceinline__ float fast_tanh(float x) {
    float e = __expf(2.0f * x);
    return 1.0f - 2.0f / (e + 1.0f);
}

// pack 2 f32 -> 2 bf16 (RNE) in one instr
__device__ __forceinline__ unsigned int cvt_pk_bf16(float lo, float hi) {
    unsigned int r;
    asm("v_cvt_pk_bf16_f32 %0, %1, %2" : "=v"(r) : "v"(lo), "v"(hi));
    return r;
}
// 2^x directly (log2e pre-folded into the multiplier)
__device__ __forceinline__ float exp2_fast(float x) {
    float r;
    asm("v_exp_f32 %0, %1" : "=v"(r) : "v"(x));
    return r;
}
// a' = {a.q0,a.q1,b.q0,b.q1}, b' = {a.q2,a.q3,b.q2,b.q3}  (16-lane rows)
__device__ __forceinline__ void swap32(unsigned int &a, unsigned int &b) {
    asm("v_permlane32_swap_b32 %0, %1" : "+v"(a), "+v"(b));
}
// a' = {a.q0,b.q0,a.q2,b.q2}, b' = {a.q1,b.q1,a.q3,b.q3}
__device__ __forceinline__ void swap16(unsigned int &a, unsigned int &b) {
    asm("v_permlane16_swap_b32 %0, %1" : "+v"(a), "+v"(b));
}

// XOR-swizzled LDS byte offset: rows of 128B, 16B chunks swizzled by row&7.
// Measured 0 bank conflicts for the K staging + frag-read pattern (round 2).
__device__ __forceinline__ int swb(int row, int byteoff) {
    return row * 128 + ((((byteoff >> 4) ^ (row & 7)) << 4) | (byteoff & 15));
}

// ---------------------------------------------------------------------------
// K0 (fused preprocessing, partitioned grid):
//  blocks [0,2048):    q transform  -> qt  [B,H,L,E] bf16
//  blocks [2048,4096): k transform  -> kt  [B,H,S,E] bf16
//  blocks [4096,5120): v transform  -> vt  MFMA-frag-tiled bf16:
//        vt[bh][st][ri*8+j], ri = et*128+c*64+quad*16+m,
//        value = V[b][st*64 + c*32+quad*8+j][h][et*16+m]
//        -> attn's vf[c][et] load is contiguous: lane reads ri=own, 16B.
// transform: std over H axis (8 vals, ddof=1); tanh(x*dw/(std+eps))*dp
// ---------------------------------------------------------------------------
__global__ __launch_bounds__(256) void pre_kernel(
    const float* __restrict__ xq, const float* __restrict__ xk,
    const float* __restrict__ xv,
    unsigned short* __restrict__ qt, unsigned short* __restrict__ kt,
    unsigned short* __restrict__ vt,
    const float* __restrict__ dwp, const float* __restrict__ dpp)
{
    __shared__ float ls[64][65];
    int bx = blockIdx.x;
    if (bx < 4096) {
        const float* x = (bx < 2048) ? xq : xk;
        unsigned short* xt = (bx < 2048) ? qt : kt;
        int g = (bx & 2047) * 256 + threadIdx.x;   // over B*L*E = 524288
        int e = g & 63;
        int bl = g >> 6;
        int b = bl >> 11;
        int l = bl & 2047;
        size_t base = (size_t)bl * (H_ * E_) + e;
        float v[8], s = 0.f, q = 0.f;
#pragma unroll
        for (int h = 0; h < 8; ++h) {
            float t = x[base + h * E_];
            v[h] = t; s += t; q += t * t;
        }
        float mean = s * 0.125f;
        float var = (q - s * mean) * (1.f / 7.f);   // ddof=1, N=8
        var = fmaxf(var, 0.f);
        float inv = 1.f / (sqrtf(var) + EPS);
        float wsc = dwp[0] * inv;
        float d = dpp[0];
#pragma unroll
        for (int h = 0; h < 8; ++h) {
            float t = fast_tanh(v[h] * wsc) * d;
            xt[((size_t)(b * H_ + h) * L_ + l) * E_ + e] = f2bf(t);
        }
    } else {
        int t2 = bx - 4096;
        int s0 = (t2 & 31) * 64;
        int h = (t2 >> 5) & 7, b = t2 >> 8;
        int t = threadIdx.x;
#pragma unroll
        for (int i = 0; i < 4; ++i) {
            int idx = t + i * 256;
            int r = idx >> 4, c4 = (idx & 15) * 4;
            const float4 f = *(const float4*)&xv[((size_t)(b * S_ + s0 + r) * H_ + h) * E_ + c4];
            ls[r][c4] = f.x; ls[r][c4 + 1] = f.y; ls[r][c4 + 2] = f.z; ls[r][c4 + 3] = f.w;
        }
        __syncthreads();
        size_t ob = ((size_t)(b * H_ + h) * (S_ / 64) + (s0 >> 6)) * 4096;
#pragma unroll
        for (int i = 0; i < 2; ++i) {
            int ri = t + i * 256;                  // 512 runs of 8 halfwords
            int et = ri >> 7, c = (ri >> 6) & 1, quad = (ri >> 4) & 3, m = ri & 15;
            int e = et * 16 + m, sb = c * 32 + quad * 8;
            unsigned short tmp[8];
#pragma unroll
            for (int j = 0; j < 8; ++j) tmp[j] = f2bf(ls[sb + j][e]);
            *(uint4*)&vt[ob + (size_t)ri * 8] = *(uint4*)tmp;
        }
    }
}

// ---------------------------------------------------------------------------
// K1: per (b,h): G = Kt^T Kt (64x64 f32 acc -> bf16) + ksum[e] = sum_s kt.
// 32 blocks, 256 thr. Reads kt in 16 chunks of 128 s (reg-prefetched),
// in-LDS transpose for the A==B fragments, 256 MFMA/wave, 4-wave reduce.
// ---------------------------------------------------------------------------
__global__ __launch_bounds__(256) void gram_kernel(
    const unsigned short* __restrict__ kt, unsigned short* __restrict__ Gb,
    float* __restrict__ ksum)
{
    __shared__ unsigned short ks[128 * 72];   // pad 72: transpose-friendly
    __shared__ float gs[4096];
    __shared__ float kss[64];
    int bh = blockIdx.x;
    const unsigned short* base = kt + (size_t)bh * S_ * E_;
    int tid = threadIdx.x, lane = tid & 63, w = tid >> 6;
    int m = lane & 15, quad = lane >> 4;

    f32x4 acc[4][4];
#pragma unroll
    for (int i = 0; i < 4; ++i)
#pragma unroll
        for (int j = 0; j < 4; ++j) acc[i][j] = (f32x4){0.f, 0.f, 0.f, 0.f};
    float ksp[4] = {0.f, 0.f, 0.f, 0.f};

    short8 stg[4];
#pragma unroll
    for (int i = 0; i < 4; ++i)
        stg[i] = *(const short8*)(base + (size_t)(tid + i * 256) * 8);

    for (int ch = 0; ch < 16; ++ch) {
        __syncthreads();                       // prior readers of ks done
#pragma unroll
        for (int i = 0; i < 4; ++i) {
            int u = tid + i * 256;
            *(short8*)&ks[(u >> 3) * 72 + (u & 7) * 8] = stg[i];
        }
        __syncthreads();
        if (ch < 15) {
#pragma unroll
            for (int i = 0; i < 4; ++i)
                stg[i] = *(const short8*)(base + (size_t)(ch + 1) * 8192 + (tid + i * 256) * 8);
        }
        int s0 = w * 32;
        short8 af[4];
#pragma unroll
        for (int i = 0; i < 4; ++i) {
            short8 a;
#pragma unroll
            for (int kk = 0; kk < 8; ++kk) {
                unsigned short uv = ks[(s0 + quad * 8 + kk) * 72 + i * 16 + m];
                a[kk] = (short)uv;
                ksp[i] += bf2f(uv);
            }
            af[i] = a;
        }
#pragma unroll
        for (int i = 0; i < 4; ++i)
#pragma unroll
            for (int j = 0; j < 4; ++j)
                acc[i][j] = __builtin_amdgcn_mfma_f32_16x16x32_bf16(af[i], af[j], acc[i][j], 0, 0, 0);
    }
#pragma unroll
    for (int i = 0; i < 4; ++i) {
        ksp[i] += __shfl_xor(ksp[i], 16);
        ksp[i] += __shfl_xor(ksp[i], 32);
    }
    for (int w2 = 0; w2 < 4; ++w2) {
        if (w == w2) {
#pragma unroll
            for (int i = 0; i < 4; ++i)
#pragma unroll
                for (int j = 0; j < 4; ++j)
#pragma unroll
                    for (int r = 0; r < 4; ++r) {
                        int idx = (i * 16 + quad * 4 + r) * 64 + j * 16 + m;
                        if (w2 == 0) gs[idx] = acc[i][j][r]; else gs[idx] += acc[i][j][r];
                    }
            if (lane < 16) {
#pragma unroll
                for (int i = 0; i < 4; ++i) {
                    int e = i * 16 + lane;
                    if (w2 == 0) kss[e] = ksp[i]; else kss[e] += ksp[i];
                }
            }
        }
        __syncthreads();
    }
#pragma unroll
    for (int ii = 0; ii < 16; ++ii) {
        int idx = tid + ii * 256;
        Gb[(size_t)bh * 4096 + idx] = f2bf(gs[idx]);
    }
    if (tid < 64) ksum[bh * 64 + tid] = kss[tid];
}

// ---------------------------------------------------------------------------
// K2: single-pass attention. ROUND-6: in-register P (T12 pattern).
// 8 waves x 16 q-rows; score layout already has lane m = q-row, so the PV
// A-frag is built in-register: 8 x v_cvt_pk_bf16_f32 + 8 x permlane swaps
// replace the P LDS round-trip (removes 6 DS instrs/wave/iter + two ~120cy
// lgkm hops from the serial chain; frees 16KB LDS). exp2-folding deletes
// the v_mul inside __expf. Denominator comes from an extra ones-MFMA
// (exact row-sums of stored bf16 P, lands at the output row's lane ->
// kills 16 VALU adds/iter AND the final shuffle reduce).
// Route (derived, verified by layout algebra):
//   target pf_c word t needs W[2c + q1][t&1] from source quad 2*q0 + (t>>1)
//   => per (c,u): a=W[2c][u], b=W[2c+1][u]; swap32(a,b); swap16(a,b);
//      pf_c = {a_u0, a_u1, b_u0, b_u1}.
// ---------------------------------------------------------------------------
__global__ __launch_bounds__(512, 4) void attn_kernel(
    const unsigned short* __restrict__ qt,
    const unsigned short* __restrict__ kt,
    const unsigned short* __restrict__ vt,
    const unsigned short* __restrict__ Gb,
    const float* __restrict__ ksum,
    float* __restrict__ out)
{
    __shared__ __align__(16) char lds[17408];
    // [0,16384): K double buffer (2 x 8KB, swizzled 128B rows)
    // [16384,17408): alpha scratch (8 x 16 float2)
    const int tid = threadIdx.x;
    const int lane = tid & 63;
    const int w = tid >> 6;
    const int m = lane & 15;
    const int quad = lane >> 4;
    float2* ascr = (float2*)(lds + 16384) + w * 16;

    int blk = blockIdx.x;
    int bh = (blk & 7) * 4 + ((blk >> 3) & 3);   // XCD swizzle: 4 bh per XCD
    int l0 = (blk >> 5) * 128;
    int b = bh >> 3, h = bh & 7;

    const unsigned short* qtb = qt + (size_t)bh * L_ * E_;
    const unsigned short* ktb = kt + (size_t)bh * S_ * E_;
    const unsigned short* vtb = vt + (size_t)bh * (S_ / 64) * 4096;

    // Q B-fragments (register-resident): lane m <-> q-row l0 + w*16 + m
    short8 qf[2];
#pragma unroll
    for (int c = 0; c < 2; ++c)
        qf[c] = *(const short8*)(qtb + (size_t)(l0 + w * 16 + m) * E_ + c * 32 + quad * 8);

    // ---- in-block alpha: T = Q*G, sumsq = sum T.Q, rowsum = Q.ksum ----
    float al2, nalm2;   // log2e-folded: P = 2^(al2*score - alm2)
    {
        const unsigned short* gb = Gb + (size_t)bh * 4096;
        short8 gfr[4][2];
#pragma unroll
        for (int j = 0; j < 4; ++j)
#pragma unroll
            for (int c = 0; c < 2; ++c)
                gfr[j][c] = *(const short8*)(gb + (size_t)(j * 16 + m) * 64 + c * 32 + quad * 8);
        float ksl[4];
#pragma unroll
        for (int j = 0; j < 4; ++j) ksl[j] = ksum[bh * 64 + j * 16 + m];
        f32x4 accj[4];
#pragma unroll
        for (int j = 0; j < 4; ++j) {
            accj[j] = (f32x4){0.f, 0.f, 0.f, 0.f};
            accj[j] = __builtin_amdgcn_mfma_f32_16x16x32_bf16(qf[0], gfr[j][0], accj[j], 0, 0, 0);
            accj[j] = __builtin_amdgcn_mfma_f32_16x16x32_bf16(qf[1], gfr[j][1], accj[j], 0, 0, 0);
        }
        float ps[4] = {0, 0, 0, 0}, pr[4] = {0, 0, 0, 0};
#pragma unroll
        for (int r = 0; r < 4; ++r)
#pragma unroll
            for (int j = 0; j < 4; ++j) {
                float qv = bf2f(qtb[(size_t)(l0 + w * 16 + quad * 4 + r) * E_ + j * 16 + m]);
                ps[r] = fmaf(accj[j][r], qv, ps[r]);
                pr[r] = fmaf(qv, ksl[j], pr[r]);
            }
#pragma unroll
        for (int mask = 1; mask < 16; mask <<= 1)
#pragma unroll
            for (int r = 0; r < 4; ++r) {
                ps[r] += __shfl_xor(ps[r], mask);
                pr[r] += __shfl_xor(pr[r], mask);
            }
        if (m == 0) {
#pragma unroll
            for (int r = 0; r < 4; ++r) {
                float sum = pr[r];
                float mu = sum * (1.f / S_);
                float var = (ps[r] - sum * mu) * (1.f / (S_ - 1));   // ddof=1
                var = fmaxf(var, 0.f);
                float tau = sqrtf(var + EPS);
                float a = 0.125f / tau;                               // scale=1/8
                ascr[quad * 4 + r] = make_float2(a, a * mu);
            }
        }
        float2 a2 = ascr[m];   // wave-private LDS: lgkmcnt ordering suffices
        al2 = a2.x * LOG2E; nalm2 = -a2.y * LOG2E;
    }

    f32x4 oacc[4];
#pragma unroll
    for (int et = 0; et < 4; ++et) oacc[et] = (f32x4){0.f, 0.f, 0.f, 0.f};
    f32x4 asum = (f32x4){0.f, 0.f, 0.f, 0.f};   // P row-sums via ones-MFMA

    // ones B-fragment (bf16 1.0 everywhere)
    short8 ones;
#pragma unroll
    for (int j = 0; j < 8; ++j) ones[j] = (short)0x3F80;

    // ---- hoisted swizzled LDS offsets (loop-invariant, stay in VGPRs) ----
    int ko[4];
#pragma unroll
    for (int nt = 0; nt < 4; ++nt)
        ko[nt] = swb(nt * 16 + m, quad * 16);        // K frag read (c=0); c=1 is ^64
    const int stg = swb(tid >> 3, (tid & 7) * 16);   // K stage write (1 uint4/thread)

    // preload K tile 0 (8KB = 512 uint4, 1 per thread)
    uint4 kr = *(const uint4*)(ktb + (size_t)tid * 8);
    *(uint4*)(lds + stg) = kr;
    __syncthreads();

    auto step = [&](int st, char* kcur, char* knxt) {
        // prefetch next K tile into registers (covered by loop-end barrier)
        if (st < S_ / 64 - 1)
            kr = *(const uint4*)(ktb + (size_t)(st + 1) * 4096 + (size_t)tid * 8);
        // V B-frags: contiguous 1KB wave-loads from frag-tiled vt
        const unsigned short* vstb = vtb + (size_t)st * 4096;
        short8 vf[2][4];
#pragma unroll
        for (int c = 0; c < 2; ++c)
#pragma unroll
            for (int et = 0; et < 4; ++et)
                vf[c][et] = *(const short8*)(vstb + et * 1024 + c * 512 + lane * 8);

        // QK + softmax, packed in-register: W[nt][u] = bf16pair(p[2u],p[2u+1])
        unsigned int W[4][2];
#pragma unroll
        for (int nt = 0; nt < 4; ++nt) {
            short8 kf0 = *(const short8*)(kcur + ko[nt]);
            short8 kf1 = *(const short8*)(kcur + (ko[nt] ^ 64));
            f32x4 acc = (f32x4){0.f, 0.f, 0.f, 0.f};
            acc = __builtin_amdgcn_mfma_f32_16x16x32_bf16(kf0, qf[0], acc, 0, 0, 0);
            acc = __builtin_amdgcn_mfma_f32_16x16x32_bf16(kf1, qf[1], acc, 0, 0, 0);
            float p0 = exp2_fast(fmaf(al2, acc[0], nalm2));
            float p1 = exp2_fast(fmaf(al2, acc[1], nalm2));
            float p2 = exp2_fast(fmaf(al2, acc[2], nalm2));
            float p3 = exp2_fast(fmaf(al2, acc[3], nalm2));
            W[nt][0] = cvt_pk_bf16(p0, p1);
            W[nt][1] = cvt_pk_bf16(p2, p3);
        }
        // in-register P redistribution -> PV A-frags (no LDS round-trip)
        short8 pf[2];
#pragma unroll
        for (int c = 0; c < 2; ++c) {
            unsigned int a0 = W[2 * c][0], b0 = W[2 * c + 1][0];
            unsigned int a1 = W[2 * c][1], b1 = W[2 * c + 1][1];
            swap32(a0, b0); swap16(a0, b0);
            swap32(a1, b1); swap16(a1, b1);
            uint4 pk4;
            pk4.x = a0; pk4.y = a1; pk4.z = b0; pk4.w = b1;
            pf[c] = *(short8*)&pk4;
        }
        // PV + denominator (ones-MFMA: exact row-sum of stored bf16 P)
#pragma unroll
        for (int et = 0; et < 4; ++et) {
            oacc[et] = __builtin_amdgcn_mfma_f32_16x16x32_bf16(pf[0], vf[0][et], oacc[et], 0, 0, 0);
            oacc[et] = __builtin_amdgcn_mfma_f32_16x16x32_bf16(pf[1], vf[1][et], oacc[et], 0, 0, 0);
        }
        asum = __builtin_amdgcn_mfma_f32_16x16x32_bf16(pf[0], ones, asum, 0, 0, 0);
        asum = __builtin_amdgcn_mfma_f32_16x16x32_bf16(pf[1], ones, asum, 0, 0, 0);
        // write prefetched K to the other buffer; single barrier per iter.
        // (all waves are in the same st between barriers -> read buf != write buf)
        if (st < S_ / 64 - 1)
            *(uint4*)(knxt + stg) = kr;
        __syncthreads();
    };
#pragma unroll 1
    for (int st2 = 0; st2 < S_ / 128; ++st2) {
        step(2 * st2,     lds,        lds + 8192);   // compile-time buffer select
        step(2 * st2 + 1, lds + 8192, lds);
    }

    // store: asum[r] is already the full denominator for q-row quad*4+r
#pragma unroll
    for (int r = 0; r < 4; ++r) {
        float rd = 1.0f / asum[r];
        size_t row = (size_t)(b * L_ + l0 + w * 16 + quad * 4 + r);
#pragma unroll
        for (int et = 0; et < 4; ++et)
            out[(row * H_ + h) * E_ + et * 16 + m] = oacc[et][r] * rd;
    }
}

extern "C" void kernel_launch(void* const* d_in, const int* in_sizes, int n_in,
                              void* d_out, int out_size, void* d_ws, size_t ws_size,
                              hipStream_t stream)
{
    const float* q = (const float*)d_in[0];
    const float* k = (const float*)d_in[1];
    const float* v = (const float*)d_in[2];
    // d_in[3] = attn_mask (unused)
    const float* dw = (const float*)d_in[4];
    const float* dp = (const float*)d_in[5];
    float* out = (float*)d_out;

    unsigned short* qt = (unsigned short*)d_ws;              // [B,H,L,E] bf16, 8MB
    unsigned short* kt = qt + (size_t)BH_ * L_ * E_;         // [B,H,S,E] bf16, 8MB
    unsigned short* vt = kt + (size_t)BH_ * S_ * E_;         // frag-tiled, 8MB
    unsigned short* Gb = vt + (size_t)BH_ * E_ * S_;         // [B,H,64,64] bf16
    float* ksum = (float*)(Gb + (size_t)BH_ * 4096);         // [B,H,64]

    pre_kernel<<<5120, 256, 0, stream>>>(q, k, v, qt, kt, vt, dw, dp);
    gram_kernel<<<BH_, 256, 0, stream>>>(kt, Gb, ksum);
    attn_kernel<<<512, 512, 0, stream>>>(qt, kt, vt, Gb, ksum, out);
}

// Round 3
// 163.362 us; speedup vs baseline: 1.0762x; 1.0333x over previous
//
#include <hip/hip_runtime.h>
#include <math.h>

#define B_ 4
#define L_ 2048
#define S_ 2048
#define H_ 8
#define E_ 64
#define BH_ (B_*H_)
#define EPS 1e-6f
#define LOG2E 1.44269504088896340736f

typedef __attribute__((ext_vector_type(8))) short short8;
typedef __attribute__((ext_vector_type(4))) float f32x4;

__device__ __forceinline__ unsigned short f2bf(float f) {
    unsigned int u = __float_as_uint(f);
    u = (u + 0x7fffu + ((u >> 16) & 1u)) >> 16;   // RNE
    return (unsigned short)u;
}

__device__ __forceinline__ float bf2f(unsigned short u) {
    return __uint_as_float(((unsigned int)u) << 16);
}

__device__ __forceinline__ float fast_tanh(float x) {
    float e = __expf(2.0f * x);
    return 1.0f - 2.0f / (e + 1.0f);
}

// pack 2 f32 -> 2 bf16 (RNE) in one instr
__device__ __forceinline__ unsigned int cvt_pk_bf16(float lo, float hi) {
    unsigned int r;
    asm("v_cvt_pk_bf16_f32 %0, %1, %2" : "=v"(r) : "v"(lo), "v"(hi));
    return r;
}
// 2^x directly (log2e pre-folded into the multiplier)
__device__ __forceinline__ float exp2_fast(float x) {
    float r;
    asm("v_exp_f32 %0, %1" : "=v"(r) : "v"(x));
    return r;
}
// a' = {a.q0,a.q1,b.q0,b.q1}, b' = {a.q2,a.q3,b.q2,b.q3}  (16-lane rows)
__device__ __forceinline__ void swap32(unsigned int &a, unsigned int &b) {
    asm("v_permlane32_swap_b32 %0, %1" : "+v"(a), "+v"(b));
}
// a' = {a.q0,b.q0,a.q2,b.q2}, b' = {a.q1,b.q1,a.q3,b.q3}
__device__ __forceinline__ void swap16(unsigned int &a, unsigned int &b) {
    asm("v_permlane16_swap_b32 %0, %1" : "+v"(a), "+v"(b));
}

// ---------------------------------------------------------------------------
// K0 (fused preprocessing, partitioned grid). ROUND-7 rewrite of the q/k
// transform path: 1 wave per (b,l) row; 2x float4 loads (1KB/wave-instr),
// std over H via 16 shfl_xor (lanes {l,l^16,l^32,l^48} hold h=0..7 for the
// same e), pack via v_cvt_pk_bf16_f32, 2x uint2 stores (512B/wave-instr).
// 4 memory instrs/wave vs 16 before — same math, same bytes.
//  blocks [0,2048):    q transform  -> qt  [B,H,L,E] bf16
//  blocks [2048,4096): k transform  -> kt  [B,H,S,E] bf16 (gram retiles it)
//  blocks [4096,5120): v transform  -> vt  MFMA-frag-tiled bf16 (unchanged)
// ---------------------------------------------------------------------------
__global__ __launch_bounds__(256) void pre_kernel(
    const float* __restrict__ xq, const float* __restrict__ xk,
    const float* __restrict__ xv,
    unsigned short* __restrict__ qt, unsigned short* __restrict__ kt,
    unsigned short* __restrict__ vt,
    const float* __restrict__ dwp, const float* __restrict__ dpp)
{
    __shared__ float ls[64][65];
    int bx = blockIdx.x;
    int tid = threadIdx.x;
    if (bx < 4096) {
        const float* x = (bx < 2048) ? xq : xk;
        unsigned short* xt = (bx < 2048) ? qt : kt;
        int wv = tid >> 6, ln = tid & 63;
        int bl = (bx & 2047) * 4 + wv;
        int b = bl >> 11, l = bl & 2047;
        const float* xb = x + (size_t)bl * 512;
        float4 fa = *(const float4*)(xb + ln * 4);        // h = ln>>4,   e = (ln&15)*4..+4
        float4 fb = *(const float4*)(xb + 256 + ln * 4);  // h = ln>>4+4, same e
        float s0 = fa.x + fb.x, s1 = fa.y + fb.y, s2 = fa.z + fb.z, s3 = fa.w + fb.w;
        float q0 = fa.x * fa.x + fb.x * fb.x, q1 = fa.y * fa.y + fb.y * fb.y;
        float q2 = fa.z * fa.z + fb.z * fb.z, q3 = fa.w * fa.w + fb.w * fb.w;
        // reduce over {ln^16, ln^32}: each e's 8 h-values live in that group
        s0 += __shfl_xor(s0, 16); s1 += __shfl_xor(s1, 16);
        s2 += __shfl_xor(s2, 16); s3 += __shfl_xor(s3, 16);
        q0 += __shfl_xor(q0, 16); q1 += __shfl_xor(q1, 16);
        q2 += __shfl_xor(q2, 16); q3 += __shfl_xor(q3, 16);
        s0 += __shfl_xor(s0, 32); s1 += __shfl_xor(s1, 32);
        s2 += __shfl_xor(s2, 32); s3 += __shfl_xor(s3, 32);
        q0 += __shfl_xor(q0, 32); q1 += __shfl_xor(q1, 32);
        q2 += __shfl_xor(q2, 32); q3 += __shfl_xor(q3, 32);
        float dw = dwp[0], d = dpp[0];
        auto mkw = [&](float s, float q) {
            float mean = s * 0.125f;
            float var = (q - s * mean) * (1.f / 7.f);   // ddof=1, N=8
            var = fmaxf(var, 0.f);
            return dw / (sqrtf(var) + EPS);
        };
        float w0 = mkw(s0, q0), w1 = mkw(s1, q1), w2 = mkw(s2, q2), w3 = mkw(s3, q3);
        float ta0 = fast_tanh(fa.x * w0) * d, ta1 = fast_tanh(fa.y * w1) * d;
        float ta2 = fast_tanh(fa.z * w2) * d, ta3 = fast_tanh(fa.w * w3) * d;
        float tb0 = fast_tanh(fb.x * w0) * d, tb1 = fast_tanh(fb.y * w1) * d;
        float tb2 = fast_tanh(fb.z * w2) * d, tb3 = fast_tanh(fb.w * w3) * d;
        uint2 pa, pb;
        pa.x = cvt_pk_bf16(ta0, ta1); pa.y = cvt_pk_bf16(ta2, ta3);
        pb.x = cvt_pk_bf16(tb0, tb1); pb.y = cvt_pk_bf16(tb2, tb3);
        int hh = ln >> 4, e0 = (ln & 15) * 4;
        *(uint2*)(xt + ((size_t)(b * 8 + hh) * 2048 + l) * 64 + e0) = pa;
        *(uint2*)(xt + ((size_t)(b * 8 + hh + 4) * 2048 + l) * 64 + e0) = pb;
    } else {
        int t2 = bx - 4096;
        int s0 = (t2 & 31) * 64;
        int h = (t2 >> 5) & 7, b = t2 >> 8;
        int t = tid;
#pragma unroll
        for (int i = 0; i < 4; ++i) {
            int idx = t + i * 256;
            int r = idx >> 4, c4 = (idx & 15) * 4;
            const float4 f = *(const float4*)&xv[((size_t)(b * S_ + s0 + r) * H_ + h) * E_ + c4];
            ls[r][c4] = f.x; ls[r][c4 + 1] = f.y; ls[r][c4 + 2] = f.z; ls[r][c4 + 3] = f.w;
        }
        __syncthreads();
        size_t ob = ((size_t)(b * H_ + h) * (S_ / 64) + (s0 >> 6)) * 4096;
#pragma unroll
        for (int i = 0; i < 2; ++i) {
            int ri = t + i * 256;                  // 512 runs of 8 halfwords
            int et = ri >> 7, c = (ri >> 6) & 1, quad = (ri >> 4) & 3, m = ri & 15;
            int e = et * 16 + m, sb = c * 32 + quad * 8;
            unsigned short tmp[8];
#pragma unroll
            for (int j = 0; j < 8; ++j) tmp[j] = f2bf(ls[sb + j][e]);
            *(uint4*)&vt[ob + (size_t)ri * 8] = *(uint4*)tmp;
        }
    }
}

// ---------------------------------------------------------------------------
// K1: per (b,h): G = Kt^T Kt (64x64 f32 acc -> bf16) + ksum[e] = sum_s kt.
// ROUND-7 addition: in-place frag-retile of kt. Each staged 128-s chunk is
// written BACK over its own kt bytes in MFMA A-frag order (matching vt's
// tiling), so attn's K loads become contiguous 1KB wave-loads with no LDS
// staging and no barriers. Safe: chunk ch is retiled only after it is in
// LDS and after the ch+1 prefetch has been issued; blocks are per-bh.
// ---------------------------------------------------------------------------
__global__ __launch_bounds__(256) void gram_kernel(
    unsigned short* __restrict__ kt, unsigned short* __restrict__ Gb,
    float* __restrict__ ksum)
{
    __shared__ unsigned short ks[128 * 72];   // pad 72: transpose-friendly
    __shared__ float gs[4096];
    __shared__ float kss[64];
    int bh = blockIdx.x;
    unsigned short* base = kt + (size_t)bh * S_ * E_;
    int tid = threadIdx.x, lane = tid & 63, w = tid >> 6;
    int m = lane & 15, quad = lane >> 4;

    f32x4 acc[4][4];
#pragma unroll
    for (int i = 0; i < 4; ++i)
#pragma unroll
        for (int j = 0; j < 4; ++j) acc[i][j] = (f32x4){0.f, 0.f, 0.f, 0.f};
    float ksp[4] = {0.f, 0.f, 0.f, 0.f};

    short8 stg[4];
#pragma unroll
    for (int i = 0; i < 4; ++i)
        stg[i] = *(const short8*)(base + (size_t)(tid + i * 256) * 8);

    for (int ch = 0; ch < 16; ++ch) {
        __syncthreads();                       // prior readers of ks done
#pragma unroll
        for (int i = 0; i < 4; ++i) {
            int u = tid + i * 256;
            *(short8*)&ks[(u >> 3) * 72 + (u & 7) * 8] = stg[i];
        }
        __syncthreads();
        if (ch < 15) {
#pragma unroll
            for (int i = 0; i < 4; ++i)
                stg[i] = *(const short8*)(base + (size_t)(ch + 1) * 8192 + (tid + i * 256) * 8);
        }
        // in-place frag-retile of chunk ch (2 tiles of 64 s each):
        // attn reads kf[nt][c] = 16B at tile*4096 + (nt*2+c)*512 + lane*8,
        // element j = K[s = st*64+nt*16+(lane&15)][e = c*32+(lane>>4)*8+j]
#pragma unroll
        for (int tt = 0; tt < 2; ++tt)
#pragma unroll
            for (int i = 0; i < 2; ++i) {
                int u = tid + i * 256;
                int nt = u >> 7, cc = (u >> 6) & 1, ln2 = u & 63;
                int mm = ln2 & 15, qq = ln2 >> 4;
                short8 vv = *(const short8*)&ks[(tt * 64 + nt * 16 + mm) * 72 + cc * 32 + qq * 8];
                *(uint4*)&base[(size_t)(ch * 2 + tt) * 4096 + (size_t)u * 8] = *(uint4*)&vv;
            }
        int s0 = w * 32;
        short8 af[4];
#pragma unroll
        for (int i = 0; i < 4; ++i) {
            short8 a;
#pragma unroll
            for (int kk = 0; kk < 8; ++kk) {
                unsigned short uv = ks[(s0 + quad * 8 + kk) * 72 + i * 16 + m];
                a[kk] = (short)uv;
                ksp[i] += bf2f(uv);
            }
            af[i] = a;
        }
#pragma unroll
        for (int i = 0; i < 4; ++i)
#pragma unroll
            for (int j = 0; j < 4; ++j)
                acc[i][j] = __builtin_amdgcn_mfma_f32_16x16x32_bf16(af[i], af[j], acc[i][j], 0, 0, 0);
    }
#pragma unroll
    for (int i = 0; i < 4; ++i) {
        ksp[i] += __shfl_xor(ksp[i], 16);
        ksp[i] += __shfl_xor(ksp[i], 32);
    }
    for (int w2 = 0; w2 < 4; ++w2) {
        if (w == w2) {
#pragma unroll
            for (int i = 0; i < 4; ++i)
#pragma unroll
                for (int j = 0; j < 4; ++j)
#pragma unroll
                    for (int r = 0; r < 4; ++r) {
                        int idx = (i * 16 + quad * 4 + r) * 64 + j * 16 + m;
                        if (w2 == 0) gs[idx] = acc[i][j][r]; else gs[idx] += acc[i][j][r];
                    }
            if (lane < 16) {
#pragma unroll
                for (int i = 0; i < 4; ++i) {
                    int e = i * 16 + lane;
                    if (w2 == 0) kss[e] = ksp[i]; else kss[e] += ksp[i];
                }
            }
        }
        __syncthreads();
    }
#pragma unroll
    for (int ii = 0; ii < 16; ++ii) {
        int idx = tid + ii * 256;
        Gb[(size_t)bh * 4096 + idx] = f2bf(gs[idx]);
    }
    if (tid < 64) ksum[bh * 64 + tid] = kss[tid];
}

// ---------------------------------------------------------------------------
// K2: single-pass attention. ROUND-7: zero-LDS, zero-barrier loop.
// 4 waves x 32 q-rows (per-work K/V reads halved vs 16-row waves); both K
// (frag-retiled in kt by gram) and V load DIRECT from global as contiguous
// 1KB wave-loads, L1-resident (32KB working set/CU). No staging, no dbuf,
// no __syncthreads in the loop -> waves drift freely, VMEM/VALU/MFMA
// overlap across waves instead of lockstep phases. In-register P (R2's
// cvt_pk + permlane route), ones-MFMA denominator, exp2-folded alpha.
// ---------------------------------------------------------------------------
__global__ __launch_bounds__(256, 2) void attn_kernel(
    const unsigned short* __restrict__ qt,
    const unsigned short* __restrict__ ktf,   // frag-retiled by gram
    const unsigned short* __restrict__ vt,
    const unsigned short* __restrict__ Gb,
    const float* __restrict__ ksum,
    float* __restrict__ out)
{
    __shared__ float2 ascr_s[4 * 32];          // per-wave alpha scratch, 1KB
    const int tid = threadIdx.x;
    const int lane = tid & 63;
    const int w = tid >> 6;
    const int m = lane & 15;
    const int quad = lane >> 4;
    float2* ascr = ascr_s + w * 32;

    int blk = blockIdx.x;
    int bh = (blk & 7) * 4 + ((blk >> 3) & 3);   // XCD swizzle: 4 bh per XCD
    int l0 = (blk >> 5) * 128;
    int b = bh >> 3, h = bh & 7;

    const unsigned short* qtb = qt + (size_t)bh * L_ * E_;
    const unsigned short* kb  = ktf + (size_t)bh * S_ * E_;
    const unsigned short* vtb = vt + (size_t)bh * (S_ / 64) * 4096;

    // Q B-fragments: lane m <-> q-row l0 + w*32 + g*16 + m
    short8 qf[2][2];
#pragma unroll
    for (int g = 0; g < 2; ++g)
#pragma unroll
        for (int c = 0; c < 2; ++c)
            qf[g][c] = *(const short8*)(qtb + (size_t)(l0 + w * 32 + g * 16 + m) * E_ + c * 32 + quad * 8);

    // ---- in-block alpha: T = Q*G, sumsq = sum T.Q, rowsum = Q.ksum ----
    float al2[2], nalm2[2];   // log2e-folded: P = 2^(al2*score + nalm2)
    {
        const unsigned short* gb = Gb + (size_t)bh * 4096;
        short8 gfr[4][2];
#pragma unroll
        for (int j = 0; j < 4; ++j)
#pragma unroll
            for (int c = 0; c < 2; ++c)
                gfr[j][c] = *(const short8*)(gb + (size_t)(j * 16 + m) * 64 + c * 32 + quad * 8);
        float ksl[4];
#pragma unroll
        for (int j = 0; j < 4; ++j) ksl[j] = ksum[bh * 64 + j * 16 + m];
#pragma unroll
        for (int g = 0; g < 2; ++g) {
            f32x4 accj[4];
#pragma unroll
            for (int j = 0; j < 4; ++j) {
                accj[j] = (f32x4){0.f, 0.f, 0.f, 0.f};
                accj[j] = __builtin_amdgcn_mfma_f32_16x16x32_bf16(qf[g][0], gfr[j][0], accj[j], 0, 0, 0);
                accj[j] = __builtin_amdgcn_mfma_f32_16x16x32_bf16(qf[g][1], gfr[j][1], accj[j], 0, 0, 0);
            }
            float ps[4] = {0, 0, 0, 0}, pr[4] = {0, 0, 0, 0};
#pragma unroll
            for (int r = 0; r < 4; ++r)
#pragma unroll
                for (int j = 0; j < 4; ++j) {
                    float qv = bf2f(qtb[(size_t)(l0 + w * 32 + g * 16 + quad * 4 + r) * E_ + j * 16 + m]);
                    ps[r] = fmaf(accj[j][r], qv, ps[r]);
                    pr[r] = fmaf(qv, ksl[j], pr[r]);
                }
#pragma unroll
            for (int mask = 1; mask < 16; mask <<= 1)
#pragma unroll
                for (int r = 0; r < 4; ++r) {
                    ps[r] += __shfl_xor(ps[r], mask);
                    pr[r] += __shfl_xor(pr[r], mask);
                }
            if (m == 0) {
#pragma unroll
                for (int r = 0; r < 4; ++r) {
                    float sum = pr[r];
                    float mu = sum * (1.f / S_);
                    float var = (ps[r] - sum * mu) * (1.f / (S_ - 1));   // ddof=1
                    var = fmaxf(var, 0.f);
                    float tau = sqrtf(var + EPS);
                    float a = 0.125f / tau;                               // scale=1/8
                    ascr[g * 16 + quad * 4 + r] = make_float2(a, a * mu);
                }
            }
        }
#pragma unroll
        for (int g = 0; g < 2; ++g) {
            float2 a2 = ascr[g * 16 + m];   // wave-private: lgkm ordering suffices
            al2[g] = a2.x * LOG2E; nalm2[g] = -a2.y * LOG2E;
        }
    }

    f32x4 oacc[2][4];
#pragma unroll
    for (int g = 0; g < 2; ++g)
#pragma unroll
        for (int et = 0; et < 4; ++et) oacc[g][et] = (f32x4){0.f, 0.f, 0.f, 0.f};
    f32x4 asum2[2];
#pragma unroll
    for (int g = 0; g < 2; ++g) asum2[g] = (f32x4){0.f, 0.f, 0.f, 0.f};

    short8 ones;
#pragma unroll
    for (int j = 0; j < 8; ++j) ones[j] = (short)0x3F80;   // bf16 1.0

#pragma unroll 2
    for (int st = 0; st < S_ / 64; ++st) {
        const unsigned short* kstb = kb + (size_t)st * 4096;
        const unsigned short* vstb = vtb + (size_t)st * 4096;
        // K A-frags: contiguous 1KB wave-loads from frag-retiled kt
        short8 kf[4][2];
#pragma unroll
        for (int nt = 0; nt < 4; ++nt)
#pragma unroll
            for (int c = 0; c < 2; ++c)
                kf[nt][c] = *(const short8*)(kstb + (nt * 2 + c) * 512 + lane * 8);
        // V B-frags: contiguous 1KB wave-loads from frag-tiled vt
        short8 vf[2][4];
#pragma unroll
        for (int c = 0; c < 2; ++c)
#pragma unroll
            for (int et = 0; et < 4; ++et)
                vf[c][et] = *(const short8*)(vstb + et * 1024 + c * 512 + lane * 8);

        // QK + softmax, packed in-register: W[g][nt][u] = bf16pair(p[2u],p[2u+1])
        unsigned int W[2][4][2];
#pragma unroll
        for (int nt = 0; nt < 4; ++nt)
#pragma unroll
            for (int g = 0; g < 2; ++g) {
                f32x4 acc = (f32x4){0.f, 0.f, 0.f, 0.f};
                acc = __builtin_amdgcn_mfma_f32_16x16x32_bf16(kf[nt][0], qf[g][0], acc, 0, 0, 0);
                acc = __builtin_amdgcn_mfma_f32_16x16x32_bf16(kf[nt][1], qf[g][1], acc, 0, 0, 0);
                float p0 = exp2_fast(fmaf(al2[g], acc[0], nalm2[g]));
                float p1 = exp2_fast(fmaf(al2[g], acc[1], nalm2[g]));
                float p2 = exp2_fast(fmaf(al2[g], acc[2], nalm2[g]));
                float p3 = exp2_fast(fmaf(al2[g], acc[3], nalm2[g]));
                W[g][nt][0] = cvt_pk_bf16(p0, p1);
                W[g][nt][1] = cvt_pk_bf16(p2, p3);
            }
        // in-register P redistribution -> PV A-frags + PV + denominator
#pragma unroll
        for (int g = 0; g < 2; ++g) {
            short8 pf[2];
#pragma unroll
            for (int c = 0; c < 2; ++c) {
                unsigned int a0 = W[g][2 * c][0], b0 = W[g][2 * c + 1][0];
                unsigned int a1 = W[g][2 * c][1], b1 = W[g][2 * c + 1][1];
                swap32(a0, b0); swap16(a0, b0);
                swap32(a1, b1); swap16(a1, b1);
                uint4 pk4;
                pk4.x = a0; pk4.y = a1; pk4.z = b0; pk4.w = b1;
                pf[c] = *(short8*)&pk4;
            }
#pragma unroll
            for (int et = 0; et < 4; ++et) {
                oacc[g][et] = __builtin_amdgcn_mfma_f32_16x16x32_bf16(pf[0], vf[0][et], oacc[g][et], 0, 0, 0);
                oacc[g][et] = __builtin_amdgcn_mfma_f32_16x16x32_bf16(pf[1], vf[1][et], oacc[g][et], 0, 0, 0);
            }
            asum2[g] = __builtin_amdgcn_mfma_f32_16x16x32_bf16(pf[0], ones, asum2[g], 0, 0, 0);
            asum2[g] = __builtin_amdgcn_mfma_f32_16x16x32_bf16(pf[1], ones, asum2[g], 0, 0, 0);
        }
    }

    // store: asum2[g][r] is the full denominator for q-row g*16+quad*4+r
#pragma unroll
    for (int g = 0; g < 2; ++g)
#pragma unroll
        for (int r = 0; r < 4; ++r) {
            float rd = 1.0f / asum2[g][r];
            size_t row = (size_t)(b * L_ + l0 + w * 32 + g * 16 + quad * 4 + r);
#pragma unroll
            for (int et = 0; et < 4; ++et)
                out[(row * H_ + h) * E_ + et * 16 + m] = oacc[g][et][r] * rd;
        }
}

extern "C" void kernel_launch(void* const* d_in, const int* in_sizes, int n_in,
                              void* d_out, int out_size, void* d_ws, size_t ws_size,
                              hipStream_t stream)
{
    const float* q = (const float*)d_in[0];
    const float* k = (const float*)d_in[1];
    const float* v = (const float*)d_in[2];
    // d_in[3] = attn_mask (unused)
    const float* dw = (const float*)d_in[4];
    const float* dp = (const float*)d_in[5];
    float* out = (float*)d_out;

    unsigned short* qt = (unsigned short*)d_ws;              // [B,H,L,E] bf16, 8MB
    unsigned short* kt = qt + (size_t)BH_ * L_ * E_;         // [B,H,S,E] bf16 -> frag-retiled by gram
    unsigned short* vt = kt + (size_t)BH_ * S_ * E_;         // frag-tiled, 8MB
    unsigned short* Gb = vt + (size_t)BH_ * E_ * S_;         // [B,H,64,64] bf16
    float* ksum = (float*)(Gb + (size_t)BH_ * 4096);         // [B,H,64]

    pre_kernel<<<5120, 256, 0, stream>>>(q, k, v, qt, kt, vt, dw, dp);
    gram_kernel<<<BH_, 256, 0, stream>>>(kt, Gb, ksum);
    attn_kernel<<<512, 256, 0, stream>>>(qt, kt, vt, Gb, ksum, out);
}

// Round 4
// 157.907 us; speedup vs baseline: 1.1134x; 1.0345x over previous
//
#include <hip/hip_runtime.h>
#include <math.h>

#define B_ 4
#define L_ 2048
#define S_ 2048
#define H_ 8
#define E_ 64
#define BH_ (B_*H_)
#define EPS 1e-6f
#define LOG2E 1.44269504088896340736f

typedef __attribute__((ext_vector_type(8))) short short8;
typedef __attribute__((ext_vector_type(4))) float f32x4;

__device__ __forceinline__ unsigned short f2bf(float f) {
    unsigned int u = __float_as_uint(f);
    u = (u + 0x7fffu + ((u >> 16) & 1u)) >> 16;   // RNE
    return (unsigned short)u;
}

__device__ __forceinline__ float bf2f(unsigned short u) {
    return __uint_as_float(((unsigned int)u) << 16);
}

__device__ __forceinline__ float fast_tanh(float x) {
    float e = __expf(2.0f * x);
    return 1.0f - 2.0f / (e + 1.0f);
}

// pack 2 f32 -> 2 bf16 (RNE) in one instr
__device__ __forceinline__ unsigned int cvt_pk_bf16(float lo, float hi) {
    unsigned int r;
    asm("v_cvt_pk_bf16_f32 %0, %1, %2" : "=v"(r) : "v"(lo), "v"(hi));
    return r;
}
// 2^x directly (log2e pre-folded into the multiplier)
__device__ __forceinline__ float exp2_fast(float x) {
    float r;
    asm("v_exp_f32 %0, %1" : "=v"(r) : "v"(x));
    return r;
}
// a' = {a.q0,a.q1,b.q0,b.q1}, b' = {a.q2,a.q3,b.q2,b.q3}  (16-lane rows)
__device__ __forceinline__ void swap32(unsigned int &a, unsigned int &b) {
    asm("v_permlane32_swap_b32 %0, %1" : "+v"(a), "+v"(b));
}
// a' = {a.q0,b.q0,a.q2,b.q2}, b' = {a.q1,b.q1,a.q3,b.q3}
__device__ __forceinline__ void swap16(unsigned int &a, unsigned int &b) {
    asm("v_permlane16_swap_b32 %0, %1" : "+v"(a), "+v"(b));
}

// ---------------------------------------------------------------------------
// K0 (fused preprocessing, partitioned grid):
//  blocks [0,4096):    q/k transform (wave-per-row, 4 wide mem instrs)
//  blocks [4096,5120): v transform -> vt MFMA-frag-tiled bf16
//  blocks [5120,5152): zero-init f32 G + ksum (for gram's atomics)
// ---------------------------------------------------------------------------
__global__ __launch_bounds__(256) void pre_kernel(
    const float* __restrict__ xq, const float* __restrict__ xk,
    const float* __restrict__ xv,
    unsigned short* __restrict__ qt, unsigned short* __restrict__ kt,
    unsigned short* __restrict__ vt, float* __restrict__ Gf,
    const float* __restrict__ dwp, const float* __restrict__ dpp)
{
    __shared__ float ls[64][65];
    int bx = blockIdx.x;
    int tid = threadIdx.x;
    if (bx < 4096) {
        const float* x = (bx < 2048) ? xq : xk;
        unsigned short* xt = (bx < 2048) ? qt : kt;
        int wv = tid >> 6, ln = tid & 63;
        int bl = (bx & 2047) * 4 + wv;
        int b = bl >> 11, l = bl & 2047;
        const float* xb = x + (size_t)bl * 512;
        float4 fa = *(const float4*)(xb + ln * 4);        // h = ln>>4,   e = (ln&15)*4..+4
        float4 fb = *(const float4*)(xb + 256 + ln * 4);  // h = ln>>4+4, same e
        float s0 = fa.x + fb.x, s1 = fa.y + fb.y, s2 = fa.z + fb.z, s3 = fa.w + fb.w;
        float q0 = fa.x * fa.x + fb.x * fb.x, q1 = fa.y * fa.y + fb.y * fb.y;
        float q2 = fa.z * fa.z + fb.z * fb.z, q3 = fa.w * fa.w + fb.w * fb.w;
        // reduce over {ln^16, ln^32}: each e's 8 h-values live in that group
        s0 += __shfl_xor(s0, 16); s1 += __shfl_xor(s1, 16);
        s2 += __shfl_xor(s2, 16); s3 += __shfl_xor(s3, 16);
        q0 += __shfl_xor(q0, 16); q1 += __shfl_xor(q1, 16);
        q2 += __shfl_xor(q2, 16); q3 += __shfl_xor(q3, 16);
        s0 += __shfl_xor(s0, 32); s1 += __shfl_xor(s1, 32);
        s2 += __shfl_xor(s2, 32); s3 += __shfl_xor(s3, 32);
        q0 += __shfl_xor(q0, 32); q1 += __shfl_xor(q1, 32);
        q2 += __shfl_xor(q2, 32); q3 += __shfl_xor(q3, 32);
        float dw = dwp[0], d = dpp[0];
        auto mkw = [&](float s, float q) {
            float mean = s * 0.125f;
            float var = (q - s * mean) * (1.f / 7.f);   // ddof=1, N=8
            var = fmaxf(var, 0.f);
            return dw / (sqrtf(var) + EPS);
        };
        float w0 = mkw(s0, q0), w1 = mkw(s1, q1), w2 = mkw(s2, q2), w3 = mkw(s3, q3);
        float ta0 = fast_tanh(fa.x * w0) * d, ta1 = fast_tanh(fa.y * w1) * d;
        float ta2 = fast_tanh(fa.z * w2) * d, ta3 = fast_tanh(fa.w * w3) * d;
        float tb0 = fast_tanh(fb.x * w0) * d, tb1 = fast_tanh(fb.y * w1) * d;
        float tb2 = fast_tanh(fb.z * w2) * d, tb3 = fast_tanh(fb.w * w3) * d;
        uint2 pa, pb;
        pa.x = cvt_pk_bf16(ta0, ta1); pa.y = cvt_pk_bf16(ta2, ta3);
        pb.x = cvt_pk_bf16(tb0, tb1); pb.y = cvt_pk_bf16(tb2, tb3);
        int hh = ln >> 4, e0 = (ln & 15) * 4;
        *(uint2*)(xt + ((size_t)(b * 8 + hh) * 2048 + l) * 64 + e0) = pa;
        *(uint2*)(xt + ((size_t)(b * 8 + hh + 4) * 2048 + l) * 64 + e0) = pb;
    } else if (bx < 5120) {
        int t2 = bx - 4096;
        int s0 = (t2 & 31) * 64;
        int h = (t2 >> 5) & 7, b = t2 >> 8;
        int t = tid;
#pragma unroll
        for (int i = 0; i < 4; ++i) {
            int idx = t + i * 256;
            int r = idx >> 4, c4 = (idx & 15) * 4;
            const float4 f = *(const float4*)&xv[((size_t)(b * S_ + s0 + r) * H_ + h) * E_ + c4];
            ls[r][c4] = f.x; ls[r][c4 + 1] = f.y; ls[r][c4 + 2] = f.z; ls[r][c4 + 3] = f.w;
        }
        __syncthreads();
        size_t ob = ((size_t)(b * H_ + h) * (S_ / 64) + (s0 >> 6)) * 4096;
#pragma unroll
        for (int i = 0; i < 2; ++i) {
            int ri = t + i * 256;                  // 512 runs of 8 halfwords
            int et = ri >> 7, c = (ri >> 6) & 1, quad = (ri >> 4) & 3, m = ri & 15;
            int e = et * 16 + m, sb = c * 32 + quad * 8;
            unsigned short tmp[8];
#pragma unroll
            for (int j = 0; j < 8; ++j) tmp[j] = f2bf(ls[sb + j][e]);
            *(uint4*)&vt[ob + (size_t)ri * 8] = *(uint4*)tmp;
        }
    } else {
        // zero f32 G (32*4096) + ksum (32*64) for gram's atomic accumulate
        for (int i = (bx - 5120) * 256 + tid; i < 32 * 4096 + 32 * 64; i += 32 * 256)
            Gf[i] = 0.f;
    }
}

// ---------------------------------------------------------------------------
// K1: Gram, ROUND-8: 4-way s-split -> 128 blocks (4 per bh, 512 s each).
// 4x shorter serial chunk chain, 4x CU coverage. Partials combined with
// f32 global atomicAdd into Gf/ksum (zeroed by pre; stream order makes the
// accumulate race-free vs attn). Keeps the per-part in-place frag-retile
// of kt. No bf16 G write anymore (attn converts f32 G in its prologue).
// ---------------------------------------------------------------------------
__global__ __launch_bounds__(256) void gram_kernel(
    unsigned short* __restrict__ kt, float* __restrict__ Gf,
    float* __restrict__ ksum)
{
    __shared__ unsigned short ks[128 * 72];   // pad 72: transpose-friendly
    __shared__ float gs[4096];
    int g2 = blockIdx.x;
    int bh = g2 >> 2, part = g2 & 3;
    unsigned short* base = kt + (size_t)bh * S_ * E_ + (size_t)part * 512 * E_;
    int tid = threadIdx.x, lane = tid & 63, w = tid >> 6;
    int m = lane & 15, quad = lane >> 4;

    f32x4 acc[4][4];
#pragma unroll
    for (int i = 0; i < 4; ++i)
#pragma unroll
        for (int j = 0; j < 4; ++j) acc[i][j] = (f32x4){0.f, 0.f, 0.f, 0.f};
    float ksp[4] = {0.f, 0.f, 0.f, 0.f};

    short8 stg[4];
#pragma unroll
    for (int i = 0; i < 4; ++i)
        stg[i] = *(const short8*)(base + (size_t)(tid + i * 256) * 8);

    for (int ch = 0; ch < 4; ++ch) {
        __syncthreads();                       // prior readers of ks done
#pragma unroll
        for (int i = 0; i < 4; ++i) {
            int u = tid + i * 256;
            *(short8*)&ks[(u >> 3) * 72 + (u & 7) * 8] = stg[i];
        }
        __syncthreads();
        if (ch < 3) {
#pragma unroll
            for (int i = 0; i < 4; ++i)
                stg[i] = *(const short8*)(base + (size_t)(ch + 1) * 8192 + (tid + i * 256) * 8);
        }
        // in-place frag-retile of chunk ch (2 tiles of 64 s each):
        // attn reads kf[nt][c] = 16B at tile*4096 + (nt*2+c)*512 + lane*8,
        // element j = K[s = st*64+nt*16+(lane&15)][e = c*32+(lane>>4)*8+j]
#pragma unroll
        for (int tt = 0; tt < 2; ++tt)
#pragma unroll
            for (int i = 0; i < 2; ++i) {
                int u = tid + i * 256;
                int nt = u >> 7, cc = (u >> 6) & 1, ln2 = u & 63;
                int mm = ln2 & 15, qq = ln2 >> 4;
                short8 vv = *(const short8*)&ks[(tt * 64 + nt * 16 + mm) * 72 + cc * 32 + qq * 8];
                *(uint4*)&base[(size_t)(ch * 2 + tt) * 4096 + (size_t)u * 8] = *(uint4*)&vv;
            }
        int s0 = w * 32;
        short8 af[4];
#pragma unroll
        for (int i = 0; i < 4; ++i) {
            short8 a;
#pragma unroll
            for (int kk = 0; kk < 8; ++kk) {
                unsigned short uv = ks[(s0 + quad * 8 + kk) * 72 + i * 16 + m];
                a[kk] = (short)uv;
                ksp[i] += bf2f(uv);
            }
            af[i] = a;
        }
#pragma unroll
        for (int i = 0; i < 4; ++i)
#pragma unroll
            for (int j = 0; j < 4; ++j)
                acc[i][j] = __builtin_amdgcn_mfma_f32_16x16x32_bf16(af[i], af[j], acc[i][j], 0, 0, 0);
    }
    // ksum partial: reduce over quads in-wave, then atomic (cross-wave+cross-part)
#pragma unroll
    for (int i = 0; i < 4; ++i) {
        ksp[i] += __shfl_xor(ksp[i], 16);
        ksp[i] += __shfl_xor(ksp[i], 32);
    }
    if (lane < 16) {
#pragma unroll
        for (int i = 0; i < 4; ++i)
            atomicAdd(&ksum[bh * 64 + i * 16 + lane], ksp[i]);
    }
    // G partial: 4-wave LDS reduce, then one atomicAdd per element
    for (int w2 = 0; w2 < 4; ++w2) {
        if (w == w2) {
#pragma unroll
            for (int i = 0; i < 4; ++i)
#pragma unroll
                for (int j = 0; j < 4; ++j)
#pragma unroll
                    for (int r = 0; r < 4; ++r) {
                        int idx = (i * 16 + quad * 4 + r) * 64 + j * 16 + m;
                        if (w2 == 0) gs[idx] = acc[i][j][r]; else gs[idx] += acc[i][j][r];
                    }
        }
        __syncthreads();
    }
#pragma unroll
    for (int ii = 0; ii < 16; ++ii) {
        int idx = tid + ii * 256;
        atomicAdd(&Gf[bh * 4096 + idx], gs[idx]);
    }
}

// ---------------------------------------------------------------------------
// K2: single-pass attention (R3 structure: zero-LDS/zero-barrier loop,
// 4 waves x 32 q-rows, frag-tiled K/V direct from global, in-register P,
// ones-MFMA denominator). ROUND-8 deltas: G read as f32 (gram atomics) and
// converted to bf16 frags in the prologue; s_setprio(1) around the
// MFMA-dense PV/asum cluster (T5: favors MFMA waves when co-resident
// waves are issuing loads/VALU — applicable now that waves drift freely).
// ---------------------------------------------------------------------------
__global__ __launch_bounds__(256, 2) void attn_kernel(
    const unsigned short* __restrict__ qt,
    const unsigned short* __restrict__ ktf,   // frag-retiled by gram
    const unsigned short* __restrict__ vt,
    const float* __restrict__ Gf,
    const float* __restrict__ ksum,
    float* __restrict__ out)
{
    __shared__ float2 ascr_s[4 * 32];          // per-wave alpha scratch, 1KB
    const int tid = threadIdx.x;
    const int lane = tid & 63;
    const int w = tid >> 6;
    const int m = lane & 15;
    const int quad = lane >> 4;
    float2* ascr = ascr_s + w * 32;

    int blk = blockIdx.x;
    int bh = (blk & 7) * 4 + ((blk >> 3) & 3);   // XCD swizzle: 4 bh per XCD
    int l0 = (blk >> 5) * 128;
    int b = bh >> 3, h = bh & 7;

    const unsigned short* qtb = qt + (size_t)bh * L_ * E_;
    const unsigned short* kb  = ktf + (size_t)bh * S_ * E_;
    const unsigned short* vtb = vt + (size_t)bh * (S_ / 64) * 4096;

    // Q B-fragments: lane m <-> q-row l0 + w*32 + g*16 + m
    short8 qf[2][2];
#pragma unroll
    for (int g = 0; g < 2; ++g)
#pragma unroll
        for (int c = 0; c < 2; ++c)
            qf[g][c] = *(const short8*)(qtb + (size_t)(l0 + w * 32 + g * 16 + m) * E_ + c * 32 + quad * 8);

    // ---- in-block alpha: T = Q*G, sumsq = sum T.Q, rowsum = Q.ksum ----
    float al2[2], nalm2[2];   // log2e-folded: P = 2^(al2*score + nalm2)
    {
        const float* gb = Gf + (size_t)bh * 4096;
        short8 gfr[4][2];
#pragma unroll
        for (int j = 0; j < 4; ++j)
#pragma unroll
            for (int c = 0; c < 2; ++c) {
                const float* gp = gb + (size_t)(j * 16 + m) * 64 + c * 32 + quad * 8;
                float4 f0 = *(const float4*)gp;
                float4 f1 = *(const float4*)(gp + 4);
                uint4 u;
                u.x = cvt_pk_bf16(f0.x, f0.y); u.y = cvt_pk_bf16(f0.z, f0.w);
                u.z = cvt_pk_bf16(f1.x, f1.y); u.w = cvt_pk_bf16(f1.z, f1.w);
                gfr[j][c] = *(short8*)&u;
            }
        float ksl[4];
#pragma unroll
        for (int j = 0; j < 4; ++j) ksl[j] = ksum[bh * 64 + j * 16 + m];
#pragma unroll
        for (int g = 0; g < 2; ++g) {
            f32x4 accj[4];
#pragma unroll
            for (int j = 0; j < 4; ++j) {
                accj[j] = (f32x4){0.f, 0.f, 0.f, 0.f};
                accj[j] = __builtin_amdgcn_mfma_f32_16x16x32_bf16(qf[g][0], gfr[j][0], accj[j], 0, 0, 0);
                accj[j] = __builtin_amdgcn_mfma_f32_16x16x32_bf16(qf[g][1], gfr[j][1], accj[j], 0, 0, 0);
            }
            float ps[4] = {0, 0, 0, 0}, pr[4] = {0, 0, 0, 0};
#pragma unroll
            for (int r = 0; r < 4; ++r)
#pragma unroll
                for (int j = 0; j < 4; ++j) {
                    float qv = bf2f(qtb[(size_t)(l0 + w * 32 + g * 16 + quad * 4 + r) * E_ + j * 16 + m]);
                    ps[r] = fmaf(accj[j][r], qv, ps[r]);
                    pr[r] = fmaf(qv, ksl[j], pr[r]);
                }
#pragma unroll
            for (int mask = 1; mask < 16; mask <<= 1)
#pragma unroll
                for (int r = 0; r < 4; ++r) {
                    ps[r] += __shfl_xor(ps[r], mask);
                    pr[r] += __shfl_xor(pr[r], mask);
                }
            if (m == 0) {
#pragma unroll
                for (int r = 0; r < 4; ++r) {
                    float sum = pr[r];
                    float mu = sum * (1.f / S_);
                    float var = (ps[r] - sum * mu) * (1.f / (S_ - 1));   // ddof=1
                    var = fmaxf(var, 0.f);
                    float tau = sqrtf(var + EPS);
                    float a = 0.125f / tau;                               // scale=1/8
                    ascr[g * 16 + quad * 4 + r] = make_float2(a, a * mu);
                }
            }
        }
#pragma unroll
        for (int g = 0; g < 2; ++g) {
            float2 a2 = ascr[g * 16 + m];   // wave-private: lgkm ordering suffices
            al2[g] = a2.x * LOG2E; nalm2[g] = -a2.y * LOG2E;
        }
    }

    f32x4 oacc[2][4];
#pragma unroll
    for (int g = 0; g < 2; ++g)
#pragma unroll
        for (int et = 0; et < 4; ++et) oacc[g][et] = (f32x4){0.f, 0.f, 0.f, 0.f};
    f32x4 asum2[2];
#pragma unroll
    for (int g = 0; g < 2; ++g) asum2[g] = (f32x4){0.f, 0.f, 0.f, 0.f};

    short8 ones;
#pragma unroll
    for (int j = 0; j < 8; ++j) ones[j] = (short)0x3F80;   // bf16 1.0

#pragma unroll 2
    for (int st = 0; st < S_ / 64; ++st) {
        const unsigned short* kstb = kb + (size_t)st * 4096;
        const unsigned short* vstb = vtb + (size_t)st * 4096;
        // K A-frags: contiguous 1KB wave-loads from frag-retiled kt
        short8 kf[4][2];
#pragma unroll
        for (int nt = 0; nt < 4; ++nt)
#pragma unroll
            for (int c = 0; c < 2; ++c)
                kf[nt][c] = *(const short8*)(kstb + (nt * 2 + c) * 512 + lane * 8);
        // V B-frags: contiguous 1KB wave-loads from frag-tiled vt
        short8 vf[2][4];
#pragma unroll
        for (int c = 0; c < 2; ++c)
#pragma unroll
            for (int et = 0; et < 4; ++et)
                vf[c][et] = *(const short8*)(vstb + et * 1024 + c * 512 + lane * 8);

        // QK + softmax, packed in-register: W[g][nt][u] = bf16pair(p[2u],p[2u+1])
        unsigned int W[2][4][2];
#pragma unroll
        for (int nt = 0; nt < 4; ++nt)
#pragma unroll
            for (int g = 0; g < 2; ++g) {
                f32x4 acc = (f32x4){0.f, 0.f, 0.f, 0.f};
                acc = __builtin_amdgcn_mfma_f32_16x16x32_bf16(kf[nt][0], qf[g][0], acc, 0, 0, 0);
                acc = __builtin_amdgcn_mfma_f32_16x16x32_bf16(kf[nt][1], qf[g][1], acc, 0, 0, 0);
                float p0 = exp2_fast(fmaf(al2[g], acc[0], nalm2[g]));
                float p1 = exp2_fast(fmaf(al2[g], acc[1], nalm2[g]));
                float p2 = exp2_fast(fmaf(al2[g], acc[2], nalm2[g]));
                float p3 = exp2_fast(fmaf(al2[g], acc[3], nalm2[g]));
                W[g][nt][0] = cvt_pk_bf16(p0, p1);
                W[g][nt][1] = cvt_pk_bf16(p2, p3);
            }
        // in-register P redistribution -> PV A-frags + PV + denominator
#pragma unroll
        for (int g = 0; g < 2; ++g) {
            short8 pf[2];
#pragma unroll
            for (int c = 0; c < 2; ++c) {
                unsigned int a0 = W[g][2 * c][0], b0 = W[g][2 * c + 1][0];
                unsigned int a1 = W[g][2 * c][1], b1 = W[g][2 * c + 1][1];
                swap32(a0, b0); swap16(a0, b0);
                swap32(a1, b1); swap16(a1, b1);
                uint4 pk4;
                pk4.x = a0; pk4.y = a1; pk4.z = b0; pk4.w = b1;
                pf[c] = *(short8*)&pk4;
            }
            __builtin_amdgcn_s_setprio(1);
#pragma unroll
            for (int et = 0; et < 4; ++et) {
                oacc[g][et] = __builtin_amdgcn_mfma_f32_16x16x32_bf16(pf[0], vf[0][et], oacc[g][et], 0, 0, 0);
                oacc[g][et] = __builtin_amdgcn_mfma_f32_16x16x32_bf16(pf[1], vf[1][et], oacc[g][et], 0, 0, 0);
            }
            asum2[g] = __builtin_amdgcn_mfma_f32_16x16x32_bf16(pf[0], ones, asum2[g], 0, 0, 0);
            asum2[g] = __builtin_amdgcn_mfma_f32_16x16x32_bf16(pf[1], ones, asum2[g], 0, 0, 0);
            __builtin_amdgcn_s_setprio(0);
        }
    }

    // store: asum2[g][r] is the full denominator for q-row g*16+quad*4+r
#pragma unroll
    for (int g = 0; g < 2; ++g)
#pragma unroll
        for (int r = 0; r < 4; ++r) {
            float rd = 1.0f / asum2[g][r];
            size_t row = (size_t)(b * L_ + l0 + w * 32 + g * 16 + quad * 4 + r);
#pragma unroll
            for (int et = 0; et < 4; ++et)
                out[(row * H_ + h) * E_ + et * 16 + m] = oacc[g][et][r] * rd;
        }
}

extern "C" void kernel_launch(void* const* d_in, const int* in_sizes, int n_in,
                              void* d_out, int out_size, void* d_ws, size_t ws_size,
                              hipStream_t stream)
{
    const float* q = (const float*)d_in[0];
    const float* k = (const float*)d_in[1];
    const float* v = (const float*)d_in[2];
    // d_in[3] = attn_mask (unused)
    const float* dw = (const float*)d_in[4];
    const float* dp = (const float*)d_in[5];
    float* out = (float*)d_out;

    unsigned short* qt = (unsigned short*)d_ws;              // [B,H,L,E] bf16, 8MB
    unsigned short* kt = qt + (size_t)BH_ * L_ * E_;         // [B,H,S,E] bf16 -> frag-retiled by gram
    unsigned short* vt = kt + (size_t)BH_ * S_ * E_;         // frag-tiled, 8MB
    float* Gf = (float*)(vt + (size_t)BH_ * E_ * S_);        // [B,H,64,64] f32 (atomic-accumulated)
    float* ksum = Gf + (size_t)BH_ * 4096;                   // [B,H,64] f32 (contiguous after Gf)

    pre_kernel<<<5152, 256, 0, stream>>>(q, k, v, qt, kt, vt, Gf, dw, dp);
    gram_kernel<<<128, 256, 0, stream>>>(kt, Gf, ksum);
    attn_kernel<<<512, 256, 0, stream>>>(qt, kt, vt, Gf, ksum, out);
}

// Round 5
// 157.072 us; speedup vs baseline: 1.1193x; 1.0053x over previous
//
#include <hip/hip_runtime.h>
#include <math.h>

#define B_ 4
#define L_ 2048
#define S_ 2048
#define H_ 8
#define E_ 64
#define BH_ (B_*H_)
#define EPS 1e-6f
#define LOG2E 1.44269504088896340736f

typedef __attribute__((ext_vector_type(8))) short short8;
typedef __attribute__((ext_vector_type(4))) float f32x4;

__device__ __forceinline__ unsigned short f2bf(float f) {
    unsigned int u = __float_as_uint(f);
    u = (u + 0x7fffu + ((u >> 16) & 1u)) >> 16;   // RNE
    return (unsigned short)u;
}

__device__ __forceinline__ float bf2f(unsigned short u) {
    return __uint_as_float(((unsigned int)u) << 16);
}

__device__ __forceinline__ float fast_tanh(float x) {
    float e = __expf(2.0f * x);
    return 1.0f - 2.0f / (e + 1.0f);
}

// pack 2 f32 -> 2 bf16 (RNE) in one instr
__device__ __forceinline__ unsigned int cvt_pk_bf16(float lo, float hi) {
    unsigned int r;
    asm("v_cvt_pk_bf16_f32 %0, %1, %2" : "=v"(r) : "v"(lo), "v"(hi));
    return r;
}
// 2^x directly (log2e pre-folded into the multiplier)
__device__ __forceinline__ float exp2_fast(float x) {
    float r;
    asm("v_exp_f32 %0, %1" : "=v"(r) : "v"(x));
    return r;
}
// a' = {a.q0,a.q1,b.q0,b.q1}, b' = {a.q2,a.q3,b.q2,b.q3}  (16-lane rows)
__device__ __forceinline__ void swap32(unsigned int &a, unsigned int &b) {
    asm("v_permlane32_swap_b32 %0, %1" : "+v"(a), "+v"(b));
}
// a' = {a.q0,b.q0,a.q2,b.q2}, b' = {a.q1,b.q1,a.q3,b.q3}
__device__ __forceinline__ void swap16(unsigned int &a, unsigned int &b) {
    asm("v_permlane16_swap_b32 %0, %1" : "+v"(a), "+v"(b));
}

// ---------------------------------------------------------------------------
// K0 (fused preprocessing, partitioned grid):
//  blocks [0,4096):    q/k transform (wave-per-row, 4 wide mem instrs)
//  blocks [4096,5120): v transform -> vt MFMA-frag-tiled bf16
//  blocks [5120,5152): zero-init f32 G + ksum (for gram's atomics)
// ---------------------------------------------------------------------------
__global__ __launch_bounds__(256) void pre_kernel(
    const float* __restrict__ xq, const float* __restrict__ xk,
    const float* __restrict__ xv,
    unsigned short* __restrict__ qt, unsigned short* __restrict__ kt,
    unsigned short* __restrict__ vt, float* __restrict__ Gf,
    const float* __restrict__ dwp, const float* __restrict__ dpp)
{
    __shared__ float ls[64][65];
    int bx = blockIdx.x;
    int tid = threadIdx.x;
    if (bx < 4096) {
        const float* x = (bx < 2048) ? xq : xk;
        unsigned short* xt = (bx < 2048) ? qt : kt;
        int wv = tid >> 6, ln = tid & 63;
        int bl = (bx & 2047) * 4 + wv;
        int b = bl >> 11, l = bl & 2047;
        const float* xb = x + (size_t)bl * 512;
        float4 fa = *(const float4*)(xb + ln * 4);        // h = ln>>4,   e = (ln&15)*4..+4
        float4 fb = *(const float4*)(xb + 256 + ln * 4);  // h = ln>>4+4, same e
        float s0 = fa.x + fb.x, s1 = fa.y + fb.y, s2 = fa.z + fb.z, s3 = fa.w + fb.w;
        float q0 = fa.x * fa.x + fb.x * fb.x, q1 = fa.y * fa.y + fb.y * fb.y;
        float q2 = fa.z * fa.z + fb.z * fb.z, q3 = fa.w * fa.w + fb.w * fb.w;
        // reduce over {ln^16, ln^32}: each e's 8 h-values live in that group
        s0 += __shfl_xor(s0, 16); s1 += __shfl_xor(s1, 16);
        s2 += __shfl_xor(s2, 16); s3 += __shfl_xor(s3, 16);
        q0 += __shfl_xor(q0, 16); q1 += __shfl_xor(q1, 16);
        q2 += __shfl_xor(q2, 16); q3 += __shfl_xor(q3, 16);
        s0 += __shfl_xor(s0, 32); s1 += __shfl_xor(s1, 32);
        s2 += __shfl_xor(s2, 32); s3 += __shfl_xor(s3, 32);
        q0 += __shfl_xor(q0, 32); q1 += __shfl_xor(q1, 32);
        q2 += __shfl_xor(q2, 32); q3 += __shfl_xor(q3, 32);
        float dw = dwp[0], d = dpp[0];
        auto mkw = [&](float s, float q) {
            float mean = s * 0.125f;
            float var = (q - s * mean) * (1.f / 7.f);   // ddof=1, N=8
            var = fmaxf(var, 0.f);
            return dw / (sqrtf(var) + EPS);
        };
        float w0 = mkw(s0, q0), w1 = mkw(s1, q1), w2 = mkw(s2, q2), w3 = mkw(s3, q3);
        float ta0 = fast_tanh(fa.x * w0) * d, ta1 = fast_tanh(fa.y * w1) * d;
        float ta2 = fast_tanh(fa.z * w2) * d, ta3 = fast_tanh(fa.w * w3) * d;
        float tb0 = fast_tanh(fb.x * w0) * d, tb1 = fast_tanh(fb.y * w1) * d;
        float tb2 = fast_tanh(fb.z * w2) * d, tb3 = fast_tanh(fb.w * w3) * d;
        uint2 pa, pb;
        pa.x = cvt_pk_bf16(ta0, ta1); pa.y = cvt_pk_bf16(ta2, ta3);
        pb.x = cvt_pk_bf16(tb0, tb1); pb.y = cvt_pk_bf16(tb2, tb3);
        int hh = ln >> 4, e0 = (ln & 15) * 4;
        *(uint2*)(xt + ((size_t)(b * 8 + hh) * 2048 + l) * 64 + e0) = pa;
        *(uint2*)(xt + ((size_t)(b * 8 + hh + 4) * 2048 + l) * 64 + e0) = pb;
    } else if (bx < 5120) {
        int t2 = bx - 4096;
        int s0 = (t2 & 31) * 64;
        int h = (t2 >> 5) & 7, b = t2 >> 8;
        int t = tid;
#pragma unroll
        for (int i = 0; i < 4; ++i) {
            int idx = t + i * 256;
            int r = idx >> 4, c4 = (idx & 15) * 4;
            const float4 f = *(const float4*)&xv[((size_t)(b * S_ + s0 + r) * H_ + h) * E_ + c4];
            ls[r][c4] = f.x; ls[r][c4 + 1] = f.y; ls[r][c4 + 2] = f.z; ls[r][c4 + 3] = f.w;
        }
        __syncthreads();
        size_t ob = ((size_t)(b * H_ + h) * (S_ / 64) + (s0 >> 6)) * 4096;
#pragma unroll
        for (int i = 0; i < 2; ++i) {
            int ri = t + i * 256;                  // 512 runs of 8 halfwords
            int et = ri >> 7, c = (ri >> 6) & 1, quad = (ri >> 4) & 3, m = ri & 15;
            int e = et * 16 + m, sb = c * 32 + quad * 8;
            unsigned short tmp[8];
#pragma unroll
            for (int j = 0; j < 8; ++j) tmp[j] = f2bf(ls[sb + j][e]);
            *(uint4*)&vt[ob + (size_t)ri * 8] = *(uint4*)tmp;
        }
    } else {
        // zero f32 G (32*4096) + ksum (32*64) for gram's atomic accumulate
        for (int i = (bx - 5120) * 256 + tid; i < 32 * 4096 + 32 * 64; i += 32 * 256)
            Gf[i] = 0.f;
    }
}

// ---------------------------------------------------------------------------
// K1: Gram, 4-way s-split -> 128 blocks (4 per bh, 512 s each). Partials
// combined with f32 global atomicAdd into Gf/ksum (zeroed by pre). Keeps
// the per-part in-place frag-retile of kt.
// ---------------------------------------------------------------------------
__global__ __launch_bounds__(256) void gram_kernel(
    unsigned short* __restrict__ kt, float* __restrict__ Gf,
    float* __restrict__ ksum)
{
    __shared__ unsigned short ks[128 * 72];   // pad 72: transpose-friendly
    __shared__ float gs[4096];
    int g2 = blockIdx.x;
    int bh = g2 >> 2, part = g2 & 3;
    unsigned short* base = kt + (size_t)bh * S_ * E_ + (size_t)part * 512 * E_;
    int tid = threadIdx.x, lane = tid & 63, w = tid >> 6;
    int m = lane & 15, quad = lane >> 4;

    f32x4 acc[4][4];
#pragma unroll
    for (int i = 0; i < 4; ++i)
#pragma unroll
        for (int j = 0; j < 4; ++j) acc[i][j] = (f32x4){0.f, 0.f, 0.f, 0.f};
    float ksp[4] = {0.f, 0.f, 0.f, 0.f};

    short8 stg[4];
#pragma unroll
    for (int i = 0; i < 4; ++i)
        stg[i] = *(const short8*)(base + (size_t)(tid + i * 256) * 8);

    for (int ch = 0; ch < 4; ++ch) {
        __syncthreads();                       // prior readers of ks done
#pragma unroll
        for (int i = 0; i < 4; ++i) {
            int u = tid + i * 256;
            *(short8*)&ks[(u >> 3) * 72 + (u & 7) * 8] = stg[i];
        }
        __syncthreads();
        if (ch < 3) {
#pragma unroll
            for (int i = 0; i < 4; ++i)
                stg[i] = *(const short8*)(base + (size_t)(ch + 1) * 8192 + (tid + i * 256) * 8);
        }
        // in-place frag-retile of chunk ch (2 tiles of 64 s each):
        // attn reads kf[nt][c] = 16B at tile*4096 + (nt*2+c)*512 + lane*8,
        // element j = K[s = st*64+nt*16+(lane&15)][e = c*32+(lane>>4)*8+j]
#pragma unroll
        for (int tt = 0; tt < 2; ++tt)
#pragma unroll
            for (int i = 0; i < 2; ++i) {
                int u = tid + i * 256;
                int nt = u >> 7, cc = (u >> 6) & 1, ln2 = u & 63;
                int mm = ln2 & 15, qq = ln2 >> 4;
                short8 vv = *(const short8*)&ks[(tt * 64 + nt * 16 + mm) * 72 + cc * 32 + qq * 8];
                *(uint4*)&base[(size_t)(ch * 2 + tt) * 4096 + (size_t)u * 8] = *(uint4*)&vv;
            }
        int s0 = w * 32;
        short8 af[4];
#pragma unroll
        for (int i = 0; i < 4; ++i) {
            short8 a;
#pragma unroll
            for (int kk = 0; kk < 8; ++kk) {
                unsigned short uv = ks[(s0 + quad * 8 + kk) * 72 + i * 16 + m];
                a[kk] = (short)uv;
                ksp[i] += bf2f(uv);
            }
            af[i] = a;
        }
#pragma unroll
        for (int i = 0; i < 4; ++i)
#pragma unroll
            for (int j = 0; j < 4; ++j)
                acc[i][j] = __builtin_amdgcn_mfma_f32_16x16x32_bf16(af[i], af[j], acc[i][j], 0, 0, 0);
    }
    // ksum partial: reduce over quads in-wave, then atomic (cross-wave+cross-part)
#pragma unroll
    for (int i = 0; i < 4; ++i) {
        ksp[i] += __shfl_xor(ksp[i], 16);
        ksp[i] += __shfl_xor(ksp[i], 32);
    }
    if (lane < 16) {
#pragma unroll
        for (int i = 0; i < 4; ++i)
            atomicAdd(&ksum[bh * 64 + i * 16 + lane], ksp[i]);
    }
    // G partial: 4-wave LDS reduce, then one atomicAdd per element
    for (int w2 = 0; w2 < 4; ++w2) {
        if (w == w2) {
#pragma unroll
            for (int i = 0; i < 4; ++i)
#pragma unroll
                for (int j = 0; j < 4; ++j)
#pragma unroll
                    for (int r = 0; r < 4; ++r) {
                        int idx = (i * 16 + quad * 4 + r) * 64 + j * 16 + m;
                        if (w2 == 0) gs[idx] = acc[i][j][r]; else gs[idx] += acc[i][j][r];
                    }
        }
        __syncthreads();
    }
#pragma unroll
    for (int ii = 0; ii < 16; ++ii) {
        int idx = tid + ii * 256;
        atomicAdd(&Gf[bh * 4096 + idx], gs[idx]);
    }
}

// ---------------------------------------------------------------------------
// K2: single-pass attention. ROUND-9: register double-buffered K/V
// prefetch. Zero-LDS/zero-barrier loop, 4 waves x 32 q-rows, frag-tiled
// K/V direct from global. Tile st+1's 16 VMEM loads are issued into the
// OTHER named register buffer before computing tile st (static A/B names,
// no dynamic indexing -> stays in registers), so L2 latency (~200cy) hides
// under a full iteration of compute. setprio REMOVED (R4: symmetric boost
// across identical waves = no arbitration win, -8us regression).
// In-register P (cvt_pk + permlane), ones-MFMA denominator, exp2 alpha.
// ---------------------------------------------------------------------------
__global__ __launch_bounds__(256, 2) void attn_kernel(
    const unsigned short* __restrict__ qt,
    const unsigned short* __restrict__ ktf,   // frag-retiled by gram
    const unsigned short* __restrict__ vt,
    const float* __restrict__ Gf,
    const float* __restrict__ ksum,
    float* __restrict__ out)
{
    __shared__ float2 ascr_s[4 * 32];          // per-wave alpha scratch, 1KB
    const int tid = threadIdx.x;
    const int lane = tid & 63;
    const int w = tid >> 6;
    const int m = lane & 15;
    const int quad = lane >> 4;
    float2* ascr = ascr_s + w * 32;

    int blk = blockIdx.x;
    int bh = (blk & 7) * 4 + ((blk >> 3) & 3);   // XCD swizzle: 4 bh per XCD
    int l0 = (blk >> 5) * 128;
    int b = bh >> 3, h = bh & 7;

    const unsigned short* qtb = qt + (size_t)bh * L_ * E_;
    const unsigned short* kb  = ktf + (size_t)bh * S_ * E_;
    const unsigned short* vtb = vt + (size_t)bh * (S_ / 64) * 4096;

    // Q B-fragments: lane m <-> q-row l0 + w*32 + g*16 + m
    short8 qf[2][2];
#pragma unroll
    for (int g = 0; g < 2; ++g)
#pragma unroll
        for (int c = 0; c < 2; ++c)
            qf[g][c] = *(const short8*)(qtb + (size_t)(l0 + w * 32 + g * 16 + m) * E_ + c * 32 + quad * 8);

    // ---- in-block alpha: T = Q*G, sumsq = sum T.Q, rowsum = Q.ksum ----
    float al2[2], nalm2[2];   // log2e-folded: P = 2^(al2*score + nalm2)
    {
        const float* gb = Gf + (size_t)bh * 4096;
        short8 gfr[4][2];
#pragma unroll
        for (int j = 0; j < 4; ++j)
#pragma unroll
            for (int c = 0; c < 2; ++c) {
                const float* gp = gb + (size_t)(j * 16 + m) * 64 + c * 32 + quad * 8;
                float4 f0 = *(const float4*)gp;
                float4 f1 = *(const float4*)(gp + 4);
                uint4 u;
                u.x = cvt_pk_bf16(f0.x, f0.y); u.y = cvt_pk_bf16(f0.z, f0.w);
                u.z = cvt_pk_bf16(f1.x, f1.y); u.w = cvt_pk_bf16(f1.z, f1.w);
                gfr[j][c] = *(short8*)&u;
            }
        float ksl[4];
#pragma unroll
        for (int j = 0; j < 4; ++j) ksl[j] = ksum[bh * 64 + j * 16 + m];
#pragma unroll
        for (int g = 0; g < 2; ++g) {
            f32x4 accj[4];
#pragma unroll
            for (int j = 0; j < 4; ++j) {
                accj[j] = (f32x4){0.f, 0.f, 0.f, 0.f};
                accj[j] = __builtin_amdgcn_mfma_f32_16x16x32_bf16(qf[g][0], gfr[j][0], accj[j], 0, 0, 0);
                accj[j] = __builtin_amdgcn_mfma_f32_16x16x32_bf16(qf[g][1], gfr[j][1], accj[j], 0, 0, 0);
            }
            float ps[4] = {0, 0, 0, 0}, pr[4] = {0, 0, 0, 0};
#pragma unroll
            for (int r = 0; r < 4; ++r)
#pragma unroll
                for (int j = 0; j < 4; ++j) {
                    float qv = bf2f(qtb[(size_t)(l0 + w * 32 + g * 16 + quad * 4 + r) * E_ + j * 16 + m]);
                    ps[r] = fmaf(accj[j][r], qv, ps[r]);
                    pr[r] = fmaf(qv, ksl[j], pr[r]);
                }
#pragma unroll
            for (int mask = 1; mask < 16; mask <<= 1)
#pragma unroll
                for (int r = 0; r < 4; ++r) {
                    ps[r] += __shfl_xor(ps[r], mask);
                    pr[r] += __shfl_xor(pr[r], mask);
                }
            if (m == 0) {
#pragma unroll
                for (int r = 0; r < 4; ++r) {
                    float sum = pr[r];
                    float mu = sum * (1.f / S_);
                    float var = (ps[r] - sum * mu) * (1.f / (S_ - 1));   // ddof=1
                    var = fmaxf(var, 0.f);
                    float tau = sqrtf(var + EPS);
                    float a = 0.125f / tau;                               // scale=1/8
                    ascr[g * 16 + quad * 4 + r] = make_float2(a, a * mu);
                }
            }
        }
#pragma unroll
        for (int g = 0; g < 2; ++g) {
            float2 a2 = ascr[g * 16 + m];   // wave-private: lgkm ordering suffices
            al2[g] = a2.x * LOG2E; nalm2[g] = -a2.y * LOG2E;
        }
    }

    f32x4 oacc[2][4];
#pragma unroll
    for (int g = 0; g < 2; ++g)
#pragma unroll
        for (int et = 0; et < 4; ++et) oacc[g][et] = (f32x4){0.f, 0.f, 0.f, 0.f};
    f32x4 asum2[2];
#pragma unroll
    for (int g = 0; g < 2; ++g) asum2[g] = (f32x4){0.f, 0.f, 0.f, 0.f};

    short8 ones;
#pragma unroll
    for (int j = 0; j < 8; ++j) ones[j] = (short)0x3F80;   // bf16 1.0

    auto loadKV = [&](short8 (&kf)[4][2], short8 (&vf)[2][4], int st) {
        const unsigned short* kstb = kb + (size_t)st * 4096;
        const unsigned short* vstb = vtb + (size_t)st * 4096;
#pragma unroll
        for (int nt = 0; nt < 4; ++nt)
#pragma unroll
            for (int c = 0; c < 2; ++c)
                kf[nt][c] = *(const short8*)(kstb + (nt * 2 + c) * 512 + lane * 8);
#pragma unroll
        for (int c = 0; c < 2; ++c)
#pragma unroll
            for (int et = 0; et < 4; ++et)
                vf[c][et] = *(const short8*)(vstb + et * 1024 + c * 512 + lane * 8);
    };
    auto compute = [&](short8 (&kf)[4][2], short8 (&vf)[2][4]) {
        // QK + softmax, packed in-register: W[g][nt][u] = bf16pair(p[2u],p[2u+1])
        unsigned int W[2][4][2];
#pragma unroll
        for (int nt = 0; nt < 4; ++nt)
#pragma unroll
            for (int g = 0; g < 2; ++g) {
                f32x4 acc = (f32x4){0.f, 0.f, 0.f, 0.f};
                acc = __builtin_amdgcn_mfma_f32_16x16x32_bf16(kf[nt][0], qf[g][0], acc, 0, 0, 0);
                acc = __builtin_amdgcn_mfma_f32_16x16x32_bf16(kf[nt][1], qf[g][1], acc, 0, 0, 0);
                float p0 = exp2_fast(fmaf(al2[g], acc[0], nalm2[g]));
                float p1 = exp2_fast(fmaf(al2[g], acc[1], nalm2[g]));
                float p2 = exp2_fast(fmaf(al2[g], acc[2], nalm2[g]));
                float p3 = exp2_fast(fmaf(al2[g], acc[3], nalm2[g]));
                W[g][nt][0] = cvt_pk_bf16(p0, p1);
                W[g][nt][1] = cvt_pk_bf16(p2, p3);
            }
        // in-register P redistribution -> PV A-frags + PV + denominator
#pragma unroll
        for (int g = 0; g < 2; ++g) {
            short8 pf[2];
#pragma unroll
            for (int c = 0; c < 2; ++c) {
                unsigned int a0 = W[g][2 * c][0], b0 = W[g][2 * c + 1][0];
                unsigned int a1 = W[g][2 * c][1], b1 = W[g][2 * c + 1][1];
                swap32(a0, b0); swap16(a0, b0);
                swap32(a1, b1); swap16(a1, b1);
                uint4 pk4;
                pk4.x = a0; pk4.y = a1; pk4.z = b0; pk4.w = b1;
                pf[c] = *(short8*)&pk4;
            }
#pragma unroll
            for (int et = 0; et < 4; ++et) {
                oacc[g][et] = __builtin_amdgcn_mfma_f32_16x16x32_bf16(pf[0], vf[0][et], oacc[g][et], 0, 0, 0);
                oacc[g][et] = __builtin_amdgcn_mfma_f32_16x16x32_bf16(pf[1], vf[1][et], oacc[g][et], 0, 0, 0);
            }
            asum2[g] = __builtin_amdgcn_mfma_f32_16x16x32_bf16(pf[0], ones, asum2[g], 0, 0, 0);
            asum2[g] = __builtin_amdgcn_mfma_f32_16x16x32_bf16(pf[1], ones, asum2[g], 0, 0, 0);
        }
    };

    // register double-buffer: issue tile st+1's loads before computing st
    short8 kfA[4][2], vfA[2][4], kfB[4][2], vfB[2][4];
    loadKV(kfA, vfA, 0);
#pragma unroll 1
    for (int st2 = 0; st2 < S_ / 128; ++st2) {
        loadKV(kfB, vfB, 2 * st2 + 1);
        compute(kfA, vfA);
        if (st2 < S_ / 128 - 1)
            loadKV(kfA, vfA, 2 * st2 + 2);
        compute(kfB, vfB);
    }

    // store: asum2[g][r] is the full denominator for q-row g*16+quad*4+r
#pragma unroll
    for (int g = 0; g < 2; ++g)
#pragma unroll
        for (int r = 0; r < 4; ++r) {
            float rd = 1.0f / asum2[g][r];
            size_t row = (size_t)(b * L_ + l0 + w * 32 + g * 16 + quad * 4 + r);
#pragma unroll
            for (int et = 0; et < 4; ++et)
                out[(row * H_ + h) * E_ + et * 16 + m] = oacc[g][et][r] * rd;
        }
}

extern "C" void kernel_launch(void* const* d_in, const int* in_sizes, int n_in,
                              void* d_out, int out_size, void* d_ws, size_t ws_size,
                              hipStream_t stream)
{
    const float* q = (const float*)d_in[0];
    const float* k = (const float*)d_in[1];
    const float* v = (const float*)d_in[2];
    // d_in[3] = attn_mask (unused)
    const float* dw = (const float*)d_in[4];
    const float* dp = (const float*)d_in[5];
    float* out = (float*)d_out;

    unsigned short* qt = (unsigned short*)d_ws;              // [B,H,L,E] bf16, 8MB
    unsigned short* kt = qt + (size_t)BH_ * L_ * E_;         // [B,H,S,E] bf16 -> frag-retiled by gram
    unsigned short* vt = kt + (size_t)BH_ * S_ * E_;         // frag-tiled, 8MB
    float* Gf = (float*)(vt + (size_t)BH_ * E_ * S_);        // [B,H,64,64] f32 (atomic-accumulated)
    float* ksum = Gf + (size_t)BH_ * 4096;                   // [B,H,64] f32 (contiguous after Gf)

    pre_kernel<<<5152, 256, 0, stream>>>(q, k, v, qt, kt, vt, Gf, dw, dp);
    gram_kernel<<<128, 256, 0, stream>>>(kt, Gf, ksum);
    attn_kernel<<<512, 256, 0, stream>>>(qt, kt, vt, Gf, ksum, out);
}

// Round 6
// 153.113 us; speedup vs baseline: 1.1483x; 1.0259x over previous
//
#include <hip/hip_runtime.h>
#include <math.h>

#define B_ 4
#define L_ 2048
#define S_ 2048
#define H_ 8
#define E_ 64
#define BH_ (B_*H_)
#define EPS 1e-6f
#define LOG2E 1.44269504088896340736f

typedef __attribute__((ext_vector_type(8))) short short8;
typedef __attribute__((ext_vector_type(4))) float f32x4;

__device__ __forceinline__ unsigned short f2bf(float f) {
    unsigned int u = __float_as_uint(f);
    u = (u + 0x7fffu + ((u >> 16) & 1u)) >> 16;   // RNE
    return (unsigned short)u;
}

__device__ __forceinline__ float bf2f(unsigned short u) {
    return __uint_as_float(((unsigned int)u) << 16);
}

__device__ __forceinline__ float fast_tanh(float x) {
    float e = __expf(2.0f * x);
    return 1.0f - 2.0f / (e + 1.0f);
}

// pack 2 f32 -> 2 bf16 (RNE) in one instr
__device__ __forceinline__ unsigned int cvt_pk_bf16(float lo, float hi) {
    unsigned int r;
    asm("v_cvt_pk_bf16_f32 %0, %1, %2" : "=v"(r) : "v"(lo), "v"(hi));
    return r;
}
// 2^x directly (log2e pre-folded into the multiplier)
__device__ __forceinline__ float exp2_fast(float x) {
    float r;
    asm("v_exp_f32 %0, %1" : "=v"(r) : "v"(x));
    return r;
}
// a' = {a.q0,a.q1,b.q0,b.q1}, b' = {a.q2,a.q3,b.q2,b.q3}  (16-lane rows)
__device__ __forceinline__ void swap32(unsigned int &a, unsigned int &b) {
    asm("v_permlane32_swap_b32 %0, %1" : "+v"(a), "+v"(b));
}
// a' = {a.q0,b.q0,a.q2,b.q2}, b' = {a.q1,b.q1,a.q3,b.q3}
__device__ __forceinline__ void swap16(unsigned int &a, unsigned int &b) {
    asm("v_permlane16_swap_b32 %0, %1" : "+v"(a), "+v"(b));
}

// ---------------------------------------------------------------------------
// K0 (fused preprocessing, partitioned grid):
//  blocks [0,4096):    q/k transform (wave-per-row, 4 wide mem instrs)
//  blocks [4096,5120): v transform -> vt MFMA-frag-tiled bf16
//  blocks [5120,5152): zero-init f32 G + ksum (for gram's atomics)
// ---------------------------------------------------------------------------
__global__ __launch_bounds__(256) void pre_kernel(
    const float* __restrict__ xq, const float* __restrict__ xk,
    const float* __restrict__ xv,
    unsigned short* __restrict__ qt, unsigned short* __restrict__ kt,
    unsigned short* __restrict__ vt, float* __restrict__ Gf,
    const float* __restrict__ dwp, const float* __restrict__ dpp)
{
    __shared__ float ls[64][65];
    int bx = blockIdx.x;
    int tid = threadIdx.x;
    if (bx < 4096) {
        const float* x = (bx < 2048) ? xq : xk;
        unsigned short* xt = (bx < 2048) ? qt : kt;
        int wv = tid >> 6, ln = tid & 63;
        int bl = (bx & 2047) * 4 + wv;
        int b = bl >> 11, l = bl & 2047;
        const float* xb = x + (size_t)bl * 512;
        float4 fa = *(const float4*)(xb + ln * 4);        // h = ln>>4,   e = (ln&15)*4..+4
        float4 fb = *(const float4*)(xb + 256 + ln * 4);  // h = ln>>4+4, same e
        float s0 = fa.x + fb.x, s1 = fa.y + fb.y, s2 = fa.z + fb.z, s3 = fa.w + fb.w;
        float q0 = fa.x * fa.x + fb.x * fb.x, q1 = fa.y * fa.y + fb.y * fb.y;
        float q2 = fa.z * fa.z + fb.z * fb.z, q3 = fa.w * fa.w + fb.w * fb.w;
        // reduce over {ln^16, ln^32}: each e's 8 h-values live in that group
        s0 += __shfl_xor(s0, 16); s1 += __shfl_xor(s1, 16);
        s2 += __shfl_xor(s2, 16); s3 += __shfl_xor(s3, 16);
        q0 += __shfl_xor(q0, 16); q1 += __shfl_xor(q1, 16);
        q2 += __shfl_xor(q2, 16); q3 += __shfl_xor(q3, 16);
        s0 += __shfl_xor(s0, 32); s1 += __shfl_xor(s1, 32);
        s2 += __shfl_xor(s2, 32); s3 += __shfl_xor(s3, 32);
        q0 += __shfl_xor(q0, 32); q1 += __shfl_xor(q1, 32);
        q2 += __shfl_xor(q2, 32); q3 += __shfl_xor(q3, 32);
        float dw = dwp[0], d = dpp[0];
        auto mkw = [&](float s, float q) {
            float mean = s * 0.125f;
            float var = (q - s * mean) * (1.f / 7.f);   // ddof=1, N=8
            var = fmaxf(var, 0.f);
            return dw / (sqrtf(var) + EPS);
        };
        float w0 = mkw(s0, q0), w1 = mkw(s1, q1), w2 = mkw(s2, q2), w3 = mkw(s3, q3);
        float ta0 = fast_tanh(fa.x * w0) * d, ta1 = fast_tanh(fa.y * w1) * d;
        float ta2 = fast_tanh(fa.z * w2) * d, ta3 = fast_tanh(fa.w * w3) * d;
        float tb0 = fast_tanh(fb.x * w0) * d, tb1 = fast_tanh(fb.y * w1) * d;
        float tb2 = fast_tanh(fb.z * w2) * d, tb3 = fast_tanh(fb.w * w3) * d;
        uint2 pa, pb;
        pa.x = cvt_pk_bf16(ta0, ta1); pa.y = cvt_pk_bf16(ta2, ta3);
        pb.x = cvt_pk_bf16(tb0, tb1); pb.y = cvt_pk_bf16(tb2, tb3);
        int hh = ln >> 4, e0 = (ln & 15) * 4;
        *(uint2*)(xt + ((size_t)(b * 8 + hh) * 2048 + l) * 64 + e0) = pa;
        *(uint2*)(xt + ((size_t)(b * 8 + hh + 4) * 2048 + l) * 64 + e0) = pb;
    } else if (bx < 5120) {
        int t2 = bx - 4096;
        int s0 = (t2 & 31) * 64;
        int h = (t2 >> 5) & 7, b = t2 >> 8;
        int t = tid;
#pragma unroll
        for (int i = 0; i < 4; ++i) {
            int idx = t + i * 256;
            int r = idx >> 4, c4 = (idx & 15) * 4;
            const float4 f = *(const float4*)&xv[((size_t)(b * S_ + s0 + r) * H_ + h) * E_ + c4];
            ls[r][c4] = f.x; ls[r][c4 + 1] = f.y; ls[r][c4 + 2] = f.z; ls[r][c4 + 3] = f.w;
        }
        __syncthreads();
        size_t ob = ((size_t)(b * H_ + h) * (S_ / 64) + (s0 >> 6)) * 4096;
#pragma unroll
        for (int i = 0; i < 2; ++i) {
            int ri = t + i * 256;                  // 512 runs of 8 halfwords
            int et = ri >> 7, c = (ri >> 6) & 1, quad = (ri >> 4) & 3, m = ri & 15;
            int e = et * 16 + m, sb = c * 32 + quad * 8;
            uint4 u;
            u.x = cvt_pk_bf16(ls[sb + 0][e], ls[sb + 1][e]);
            u.y = cvt_pk_bf16(ls[sb + 2][e], ls[sb + 3][e]);
            u.z = cvt_pk_bf16(ls[sb + 4][e], ls[sb + 5][e]);
            u.w = cvt_pk_bf16(ls[sb + 6][e], ls[sb + 7][e]);
            *(uint4*)&vt[ob + (size_t)ri * 8] = u;
        }
    } else {
        // zero f32 G (32*4096) + ksum (32*64) for gram's atomic accumulate
        for (int i = (bx - 5120) * 256 + tid; i < 32 * 4096 + 32 * 64; i += 32 * 256)
            Gf[i] = 0.f;
    }
}

// ---------------------------------------------------------------------------
// K1: Gram, 4-way s-split -> 128 blocks (4 per bh, 512 s each). Partials
// combined with f32 global atomicAdd into Gf/ksum (zeroed by pre). Keeps
// the per-part in-place frag-retile of kt.
// ---------------------------------------------------------------------------
__global__ __launch_bounds__(256) void gram_kernel(
    unsigned short* __restrict__ kt, float* __restrict__ Gf,
    float* __restrict__ ksum)
{
    __shared__ unsigned short ks[128 * 72];   // pad 72: transpose-friendly
    __shared__ float gs[4096];
    int g2 = blockIdx.x;
    int bh = g2 >> 2, part = g2 & 3;
    unsigned short* base = kt + (size_t)bh * S_ * E_ + (size_t)part * 512 * E_;
    int tid = threadIdx.x, lane = tid & 63, w = tid >> 6;
    int m = lane & 15, quad = lane >> 4;

    f32x4 acc[4][4];
#pragma unroll
    for (int i = 0; i < 4; ++i)
#pragma unroll
        for (int j = 0; j < 4; ++j) acc[i][j] = (f32x4){0.f, 0.f, 0.f, 0.f};
    float ksp[4] = {0.f, 0.f, 0.f, 0.f};

    short8 stg[4];
#pragma unroll
    for (int i = 0; i < 4; ++i)
        stg[i] = *(const short8*)(base + (size_t)(tid + i * 256) * 8);

    for (int ch = 0; ch < 4; ++ch) {
        __syncthreads();                       // prior readers of ks done
#pragma unroll
        for (int i = 0; i < 4; ++i) {
            int u = tid + i * 256;
            *(short8*)&ks[(u >> 3) * 72 + (u & 7) * 8] = stg[i];
        }
        __syncthreads();
        if (ch < 3) {
#pragma unroll
            for (int i = 0; i < 4; ++i)
                stg[i] = *(const short8*)(base + (size_t)(ch + 1) * 8192 + (tid + i * 256) * 8);
        }
        // in-place frag-retile of chunk ch (2 tiles of 64 s each):
        // attn reads kf[nt][c] = 16B at tile*4096 + (nt*2+c)*512 + lane*8,
        // element j = K[s = st*64+nt*16+(lane&15)][e = c*32+(lane>>4)*8+j]
#pragma unroll
        for (int tt = 0; tt < 2; ++tt)
#pragma unroll
            for (int i = 0; i < 2; ++i) {
                int u = tid + i * 256;
                int nt = u >> 7, cc = (u >> 6) & 1, ln2 = u & 63;
                int mm = ln2 & 15, qq = ln2 >> 4;
                short8 vv = *(const short8*)&ks[(tt * 64 + nt * 16 + mm) * 72 + cc * 32 + qq * 8];
                *(uint4*)&base[(size_t)(ch * 2 + tt) * 4096 + (size_t)u * 8] = *(uint4*)&vv;
            }
        int s0 = w * 32;
        short8 af[4];
#pragma unroll
        for (int i = 0; i < 4; ++i) {
            short8 a;
#pragma unroll
            for (int kk = 0; kk < 8; ++kk) {
                unsigned short uv = ks[(s0 + quad * 8 + kk) * 72 + i * 16 + m];
                a[kk] = (short)uv;
                ksp[i] += bf2f(uv);
            }
            af[i] = a;
        }
#pragma unroll
        for (int i = 0; i < 4; ++i)
#pragma unroll
            for (int j = 0; j < 4; ++j)
                acc[i][j] = __builtin_amdgcn_mfma_f32_16x16x32_bf16(af[i], af[j], acc[i][j], 0, 0, 0);
    }
    // ksum partial: reduce over quads in-wave, then atomic (cross-wave+cross-part)
#pragma unroll
    for (int i = 0; i < 4; ++i) {
        ksp[i] += __shfl_xor(ksp[i], 16);
        ksp[i] += __shfl_xor(ksp[i], 32);
    }
    if (lane < 16) {
#pragma unroll
        for (int i = 0; i < 4; ++i)
            atomicAdd(&ksum[bh * 64 + i * 16 + lane], ksp[i]);
    }
    // G partial: 4-wave LDS reduce, then one atomicAdd per element
    for (int w2 = 0; w2 < 4; ++w2) {
        if (w == w2) {
#pragma unroll
            for (int i = 0; i < 4; ++i)
#pragma unroll
                for (int j = 0; j < 4; ++j)
#pragma unroll
                    for (int r = 0; r < 4; ++r) {
                        int idx = (i * 16 + quad * 4 + r) * 64 + j * 16 + m;
                        if (w2 == 0) gs[idx] = acc[i][j][r]; else gs[idx] += acc[i][j][r];
                    }
        }
        __syncthreads();
    }
#pragma unroll
    for (int ii = 0; ii < 16; ++ii) {
        int idx = tid + ii * 256;
        atomicAdd(&Gf[bh * 4096 + idx], gs[idx]);
    }
}

// ---------------------------------------------------------------------------
// K2: single-pass attention. ROUND-10: REVERT loop to the R3-measured-best
// form (inline loads at iteration top, #pragma unroll 2, compiler-scheduled
// prefetch). Measured A/B history: R3 plain = 50.5us; +setprio = 58.5;
// explicit reg-dbuf = 57.2 -> both "optimizations" regressed; plain wins.
// Zero-LDS/zero-barrier loop, 4 waves x 32 q-rows, frag-tiled K/V direct
// from global (L2-resident), in-register P (cvt_pk + permlane), ones-MFMA
// denominator, exp2-folded alpha, f32 G from gram's atomic accumulate.
// ---------------------------------------------------------------------------
__global__ __launch_bounds__(256, 2) void attn_kernel(
    const unsigned short* __restrict__ qt,
    const unsigned short* __restrict__ ktf,   // frag-retiled by gram
    const unsigned short* __restrict__ vt,
    const float* __restrict__ Gf,
    const float* __restrict__ ksum,
    float* __restrict__ out)
{
    __shared__ float2 ascr_s[4 * 32];          // per-wave alpha scratch, 1KB
    const int tid = threadIdx.x;
    const int lane = tid & 63;
    const int w = tid >> 6;
    const int m = lane & 15;
    const int quad = lane >> 4;
    float2* ascr = ascr_s + w * 32;

    int blk = blockIdx.x;
    int bh = (blk & 7) * 4 + ((blk >> 3) & 3);   // XCD swizzle: 4 bh per XCD
    int l0 = (blk >> 5) * 128;
    int b = bh >> 3, h = bh & 7;

    const unsigned short* qtb = qt + (size_t)bh * L_ * E_;
    const unsigned short* kb  = ktf + (size_t)bh * S_ * E_;
    const unsigned short* vtb = vt + (size_t)bh * (S_ / 64) * 4096;

    // Q B-fragments: lane m <-> q-row l0 + w*32 + g*16 + m
    short8 qf[2][2];
#pragma unroll
    for (int g = 0; g < 2; ++g)
#pragma unroll
        for (int c = 0; c < 2; ++c)
            qf[g][c] = *(const short8*)(qtb + (size_t)(l0 + w * 32 + g * 16 + m) * E_ + c * 32 + quad * 8);

    // ---- in-block alpha: T = Q*G, sumsq = sum T.Q, rowsum = Q.ksum ----
    float al2[2], nalm2[2];   // log2e-folded: P = 2^(al2*score + nalm2)
    {
        const float* gb = Gf + (size_t)bh * 4096;
        short8 gfr[4][2];
#pragma unroll
        for (int j = 0; j < 4; ++j)
#pragma unroll
            for (int c = 0; c < 2; ++c) {
                const float* gp = gb + (size_t)(j * 16 + m) * 64 + c * 32 + quad * 8;
                float4 f0 = *(const float4*)gp;
                float4 f1 = *(const float4*)(gp + 4);
                uint4 u;
                u.x = cvt_pk_bf16(f0.x, f0.y); u.y = cvt_pk_bf16(f0.z, f0.w);
                u.z = cvt_pk_bf16(f1.x, f1.y); u.w = cvt_pk_bf16(f1.z, f1.w);
                gfr[j][c] = *(short8*)&u;
            }
        float ksl[4];
#pragma unroll
        for (int j = 0; j < 4; ++j) ksl[j] = ksum[bh * 64 + j * 16 + m];
#pragma unroll
        for (int g = 0; g < 2; ++g) {
            f32x4 accj[4];
#pragma unroll
            for (int j = 0; j < 4; ++j) {
                accj[j] = (f32x4){0.f, 0.f, 0.f, 0.f};
                accj[j] = __builtin_amdgcn_mfma_f32_16x16x32_bf16(qf[g][0], gfr[j][0], accj[j], 0, 0, 0);
                accj[j] = __builtin_amdgcn_mfma_f32_16x16x32_bf16(qf[g][1], gfr[j][1], accj[j], 0, 0, 0);
            }
            float ps[4] = {0, 0, 0, 0}, pr[4] = {0, 0, 0, 0};
#pragma unroll
            for (int r = 0; r < 4; ++r)
#pragma unroll
                for (int j = 0; j < 4; ++j) {
                    float qv = bf2f(qtb[(size_t)(l0 + w * 32 + g * 16 + quad * 4 + r) * E_ + j * 16 + m]);
                    ps[r] = fmaf(accj[j][r], qv, ps[r]);
                    pr[r] = fmaf(qv, ksl[j], pr[r]);
                }
#pragma unroll
            for (int mask = 1; mask < 16; mask <<= 1)
#pragma unroll
                for (int r = 0; r < 4; ++r) {
                    ps[r] += __shfl_xor(ps[r], mask);
                    pr[r] += __shfl_xor(pr[r], mask);
                }
            if (m == 0) {
#pragma unroll
                for (int r = 0; r < 4; ++r) {
                    float sum = pr[r];
                    float mu = sum * (1.f / S_);
                    float var = (ps[r] - sum * mu) * (1.f / (S_ - 1));   // ddof=1
                    var = fmaxf(var, 0.f);
                    float tau = sqrtf(var + EPS);
                    float a = 0.125f / tau;                               // scale=1/8
                    ascr[g * 16 + quad * 4 + r] = make_float2(a, a * mu);
                }
            }
        }
#pragma unroll
        for (int g = 0; g < 2; ++g) {
            float2 a2 = ascr[g * 16 + m];   // wave-private: lgkm ordering suffices
            al2[g] = a2.x * LOG2E; nalm2[g] = -a2.y * LOG2E;
        }
    }

    f32x4 oacc[2][4];
#pragma unroll
    for (int g = 0; g < 2; ++g)
#pragma unroll
        for (int et = 0; et < 4; ++et) oacc[g][et] = (f32x4){0.f, 0.f, 0.f, 0.f};
    f32x4 asum2[2];
#pragma unroll
    for (int g = 0; g < 2; ++g) asum2[g] = (f32x4){0.f, 0.f, 0.f, 0.f};

    short8 ones;
#pragma unroll
    for (int j = 0; j < 8; ++j) ones[j] = (short)0x3F80;   // bf16 1.0

#pragma unroll 2
    for (int st = 0; st < S_ / 64; ++st) {
        const unsigned short* kstb = kb + (size_t)st * 4096;
        const unsigned short* vstb = vtb + (size_t)st * 4096;
        // K A-frags: contiguous 1KB wave-loads from frag-retiled kt
        short8 kf[4][2];
#pragma unroll
        for (int nt = 0; nt < 4; ++nt)
#pragma unroll
            for (int c = 0; c < 2; ++c)
                kf[nt][c] = *(const short8*)(kstb + (nt * 2 + c) * 512 + lane * 8);
        // V B-frags: contiguous 1KB wave-loads from frag-tiled vt
        short8 vf[2][4];
#pragma unroll
        for (int c = 0; c < 2; ++c)
#pragma unroll
            for (int et = 0; et < 4; ++et)
                vf[c][et] = *(const short8*)(vstb + et * 1024 + c * 512 + lane * 8);

        // QK + softmax, packed in-register: W[g][nt][u] = bf16pair(p[2u],p[2u+1])
        unsigned int W[2][4][2];
#pragma unroll
        for (int nt = 0; nt < 4; ++nt)
#pragma unroll
            for (int g = 0; g < 2; ++g) {
                f32x4 acc = (f32x4){0.f, 0.f, 0.f, 0.f};
                acc = __builtin_amdgcn_mfma_f32_16x16x32_bf16(kf[nt][0], qf[g][0], acc, 0, 0, 0);
                acc = __builtin_amdgcn_mfma_f32_16x16x32_bf16(kf[nt][1], qf[g][1], acc, 0, 0, 0);
                float p0 = exp2_fast(fmaf(al2[g], acc[0], nalm2[g]));
                float p1 = exp2_fast(fmaf(al2[g], acc[1], nalm2[g]));
                float p2 = exp2_fast(fmaf(al2[g], acc[2], nalm2[g]));
                float p3 = exp2_fast(fmaf(al2[g], acc[3], nalm2[g]));
                W[g][nt][0] = cvt_pk_bf16(p0, p1);
                W[g][nt][1] = cvt_pk_bf16(p2, p3);
            }
        // in-register P redistribution -> PV A-frags + PV + denominator
#pragma unroll
        for (int g = 0; g < 2; ++g) {
            short8 pf[2];
#pragma unroll
            for (int c = 0; c < 2; ++c) {
                unsigned int a0 = W[g][2 * c][0], b0 = W[g][2 * c + 1][0];
                unsigned int a1 = W[g][2 * c][1], b1 = W[g][2 * c + 1][1];
                swap32(a0, b0); swap16(a0, b0);
                swap32(a1, b1); swap16(a1, b1);
                uint4 pk4;
                pk4.x = a0; pk4.y = a1; pk4.z = b0; pk4.w = b1;
                pf[c] = *(short8*)&pk4;
            }
#pragma unroll
            for (int et = 0; et < 4; ++et) {
                oacc[g][et] = __builtin_amdgcn_mfma_f32_16x16x32_bf16(pf[0], vf[0][et], oacc[g][et], 0, 0, 0);
                oacc[g][et] = __builtin_amdgcn_mfma_f32_16x16x32_bf16(pf[1], vf[1][et], oacc[g][et], 0, 0, 0);
            }
            asum2[g] = __builtin_amdgcn_mfma_f32_16x16x32_bf16(pf[0], ones, asum2[g], 0, 0, 0);
            asum2[g] = __builtin_amdgcn_mfma_f32_16x16x32_bf16(pf[1], ones, asum2[g], 0, 0, 0);
        }
    }

    // store: asum2[g][r] is the full denominator for q-row g*16+quad*4+r
#pragma unroll
    for (int g = 0; g < 2; ++g)
#pragma unroll
        for (int r = 0; r < 4; ++r) {
            float rd = 1.0f / asum2[g][r];
            size_t row = (size_t)(b * L_ + l0 + w * 32 + g * 16 + quad * 4 + r);
#pragma unroll
            for (int et = 0; et < 4; ++et)
                out[(row * H_ + h) * E_ + et * 16 + m] = oacc[g][et][r] * rd;
        }
}

extern "C" void kernel_launch(void* const* d_in, const int* in_sizes, int n_in,
                              void* d_out, int out_size, void* d_ws, size_t ws_size,
                              hipStream_t stream)
{
    const float* q = (const float*)d_in[0];
    const float* k = (const float*)d_in[1];
    const float* v = (const float*)d_in[2];
    // d_in[3] = attn_mask (unused)
    const float* dw = (const float*)d_in[4];
    const float* dp = (const float*)d_in[5];
    float* out = (float*)d_out;

    unsigned short* qt = (unsigned short*)d_ws;              // [B,H,L,E] bf16, 8MB
    unsigned short* kt = qt + (size_t)BH_ * L_ * E_;         // [B,H,S,E] bf16 -> frag-retiled by gram
    unsigned short* vt = kt + (size_t)BH_ * S_ * E_;         // frag-tiled, 8MB
    float* Gf = (float*)(vt + (size_t)BH_ * E_ * S_);        // [B,H,64,64] f32 (atomic-accumulated)
    float* ksum = Gf + (size_t)BH_ * 4096;                   // [B,H,64] f32 (contiguous after Gf)

    pre_kernel<<<5152, 256, 0, stream>>>(q, k, v, qt, kt, vt, Gf, dw, dp);
    gram_kernel<<<128, 256, 0, stream>>>(kt, Gf, ksum);
    attn_kernel<<<512, 256, 0, stream>>>(qt, kt, vt, Gf, ksum, out);
}